// Round 10
// baseline (1244.035 us; speedup 1.0000x reference)
//
#include <hip/hip_runtime.h>

#define HDIM 256
#define WDIM 256
#define HW   65536
#define CDIM 512

using bf16x8 = __attribute__((ext_vector_type(8))) short;
using f32x4  = __attribute__((ext_vector_type(4))) float;

__device__ __forceinline__ unsigned short f2bf(float f) {
    unsigned u = __builtin_bit_cast(unsigned, f);
    u += 0x7FFFu + ((u >> 16) & 1u);          // RNE
    return (unsigned short)(u >> 16);
}

__device__ __forceinline__ void gload_lds16(const void* g, void* l) {
    __builtin_amdgcn_global_load_lds((const __attribute__((address_space(1))) unsigned int*)g,
                                     (__attribute__((address_space(3))) unsigned int*)l, 16, 0, 0);
}

// ============================ fused prep (zero + all weight transforms) ============

__device__ __forceinline__ void wtrans_one(const float* __restrict__ w,
                                           unsigned short* __restrict__ wt,
                                           int COUT, int CIN, int t) {
    int oc = t / (CIN * 9);
    int rem = t - oc * (CIN * 9);
    int ci = rem / 9;
    int tap = rem - ci * 9;
    wt[(size_t)(((ci >> 5) * 9 + tap) * COUT + oc) * 32 + (ci & 31)] = f2bf(w[t]);
}

__global__ __launch_bounds__(256) void prep_all_k(int* __restrict__ cnt,
                                                  float* __restrict__ covraw,
                                                  float* __restrict__ zp,
                                                  const float* __restrict__ cw, unsigned short* __restrict__ wc,
                                                  const float* __restrict__ s1, unsigned short* __restrict__ W1s,
                                                  const float* __restrict__ s2, unsigned short* __restrict__ W2s,
                                                  const float* __restrict__ s3, unsigned short* __restrict__ W3s,
                                                  const float* __restrict__ c1, unsigned short* __restrict__ W1c,
                                                  const float* __restrict__ c2, unsigned short* __restrict__ W2c,
                                                  const float* __restrict__ c3, unsigned short* __restrict__ W3c) {
    int t = blockIdx.x * 256 + threadIdx.x;
    if (t < 8264) {
        if (t < 8) cnt[t] = 0;
        else if (t < 8200) covraw[t - 8] = 0.f;
        else if (t < 8264) zp[t - 8200] = 0.f;
        return;
    }
    t -= 8264;
    if (t < 16384) {                       // compress_w -> wc[ci/32][oc][ci%32]
        int oc = t >> 9, ci = t & 511;
        wc[(size_t)((ci >> 5) * 32 + oc) * 32 + (ci & 31)] = f2bf(cw[t]);
        return;
    }
    t -= 16384;
    if (t < 1179648) { wtrans_one(s1, W1s, 256, 512, t); return; }
    t -= 1179648;
    if (t < 294912)  { wtrans_one(s2, W2s, 128, 256, t); return; }
    t -= 294912;
    if (t < 36864)   { wtrans_one(s3, W3s, 32, 128, t); return; }
    t -= 36864;
    if (t < 1179648) { wtrans_one(c1, W1c, 256, 512, t); return; }
    t -= 1179648;
    if (t < 294912)  { wtrans_one(c2, W2c, 128, 256, t); return; }
    t -= 294912;
    if (t < 36864)   { wtrans_one(c3, W3c, 32, 128, t); return; }
}

// ============================ small kernels ============================

__global__ __launch_bounds__(256) void pack_masks_k(const int* __restrict__ cm,
                                                    const int* __restrict__ sm,
                                                    int n,
                                                    unsigned char* __restrict__ ccode,
                                                    unsigned char* __restrict__ scode,
                                                    int* __restrict__ cnt) {
    int p = blockIdx.x * 256 + threadIdx.x;
    unsigned cc = 0, sc = 0;
    for (int i = 0; i < n; ++i) {
        if (cm[i * HW + p] != 0) cc |= (1u << i);
        if (sm[i * HW + p] != 0) sc |= (1u << i);
    }
    ccode[p] = (unsigned char)cc;
    scode[p] = (unsigned char)sc;
    int lane = threadIdx.x & 63;
    for (int i = 0; i < n; ++i) {
        unsigned long long bc = __ballot((cc >> i) & 1);
        unsigned long long bs = __ballot((sc >> i) & 1);
        if (lane == 0) {
            atomicAdd(&cnt[i],     (int)__popcll(bc));
            atomicAdd(&cnt[4 + i], (int)__popcll(bs));
        }
    }
}

// vectorized: float4 pixel loads + packed uint code loads
__global__ __launch_bounds__(256) void masked_means_k(const float* __restrict__ cF,
                                                      const float* __restrict__ sF,
                                                      const unsigned char* __restrict__ ccode,
                                                      const unsigned char* __restrict__ scode,
                                                      const int* __restrict__ cnt,
                                                      float* __restrict__ cmean5,
                                                      float* __restrict__ smean5) {
    int b = blockIdx.x;
    const float* x; const unsigned char* code; const int* cn; float* mout;
    if (b < CDIM) { x = cF; code = ccode; cn = cnt;     mout = cmean5; }
    else          { x = sF; code = scode; cn = cnt + 4; mout = smean5; b -= CDIM; }
    const int c = b;
    const int t = threadIdx.x;
    const float4* x4 = (const float4*)(x + (size_t)c * HW);
    const unsigned* cd4 = (const unsigned*)code;
    float s0 = 0.f, s1 = 0.f, s2 = 0.f, s3 = 0.f;
    for (int i = t; i < HW / 4; i += 256) {
        float4 v = x4[i];
        unsigned cd = cd4[i];
        float vv;
        vv = v.x;
        if (cd & 0x01u) s0 += vv;
        if (cd & 0x02u) s1 += vv;
        if (cd & 0x04u) s2 += vv;
        if (cd & 0x08u) s3 += vv;
        vv = v.y;
        if (cd & 0x0100u) s0 += vv;
        if (cd & 0x0200u) s1 += vv;
        if (cd & 0x0400u) s2 += vv;
        if (cd & 0x0800u) s3 += vv;
        vv = v.z;
        if (cd & 0x010000u) s0 += vv;
        if (cd & 0x020000u) s1 += vv;
        if (cd & 0x040000u) s2 += vv;
        if (cd & 0x080000u) s3 += vv;
        vv = v.w;
        if (cd & 0x01000000u) s0 += vv;
        if (cd & 0x02000000u) s1 += vv;
        if (cd & 0x04000000u) s2 += vv;
        if (cd & 0x08000000u) s3 += vv;
    }
    __shared__ float red[4][256];
    red[0][t] = s0; red[1][t] = s1; red[2][t] = s2; red[3][t] = s3;
    __syncthreads();
    for (int off = 128; off; off >>= 1) {
        if (t < off) {
            red[0][t] += red[0][t + off];
            red[1][t] += red[1][t + off];
            red[2][t] += red[2][t + off];
            red[3][t] += red[3][t + off];
        }
        __syncthreads();
    }
    if (t < 4) mout[t * CDIM + c] = red[t][0] / fmaxf((float)cn[t], 1.f);
    if (t == 4) mout[4 * CDIM + c] = 0.f;
}

__global__ __launch_bounds__(256) void idx_maps_k(const unsigned char* __restrict__ ccode,
                                                  const unsigned char* __restrict__ scode,
                                                  const int* __restrict__ cnt, int n,
                                                  signed char* __restrict__ cidx,
                                                  signed char* __restrict__ sidx,
                                                  signed char* __restrict__ fidx) {
    int p = blockIdx.x * 256 + threadIdx.x;
    int cc = ccode[p], sc = scode[p];
    int ci = 4, si = 4, fi = 4;
    for (int i = 0; i < n; ++i) {
        bool cv = cnt[i] >= 10;
        bool sv = cnt[4 + i] >= 10;
        if (((cc >> i) & 1) && cv) ci = i;
        if (((sc >> i) & 1) && sv) si = i;
        if (((cc >> i) & 1) && cv && sv) fi = i;
    }
    cidx[p] = (signed char)ci;
    sidx[p] = (signed char)si;
    fidx[p] = (signed char)fi;
}

// X[512][HW] f32 -> Xt[HW][512] bf16, fused mean-sub (float4 loads, pair-packed)
__global__ __launch_bounds__(256) void trans_in_k(const float* __restrict__ X,
                                                  const float* __restrict__ mean5,
                                                  const signed char* __restrict__ idx5,
                                                  unsigned short* __restrict__ Xt) {
    __shared__ unsigned s32[64 * 33];     // [px][32 u32 + 1 pad]
    const int tid = threadIdx.x;
    const int p0 = blockIdx.x * 64;
    const int c0 = blockIdx.y * 64;
    const int cpair = tid >> 3;
    const int q = tid & 7;
    const int ch0 = c0 + cpair * 2;
    const float* X0 = X + (size_t)ch0 * HW;
    const float* X1 = X0 + HW;
#pragma unroll
    for (int k = 0; k < 2; ++k) {
        int px0 = (q + k * 8) * 4;
        float4 va = *(const float4*)(X0 + p0 + px0);
        float4 vb = *(const float4*)(X1 + p0 + px0);
        int id4 = *(const int*)(idx5 + p0 + px0);
        float a[4] = {va.x, va.y, va.z, va.w};
        float b[4] = {vb.x, vb.y, vb.z, vb.w};
#pragma unroll
        for (int j = 0; j < 4; ++j) {
            int id = (id4 >> (8 * j)) & 0xFF;
            const float* mr = mean5 + id * CDIM;
            unsigned u = (unsigned)f2bf(a[j] - mr[ch0])
                       | ((unsigned)f2bf(b[j] - mr[ch0 + 1]) << 16);
            s32[(px0 + j) * 33 + cpair] = u;
        }
    }
    __syncthreads();
    const int px = tid >> 2, h = tid & 3;
    const unsigned* rp = &s32[px * 33 + h * 8];
    uint4 u0 = *(const uint4*)(rp);
    uint4 u1 = *(const uint4*)(rp + 4);
    unsigned short* dst = Xt + (size_t)(p0 + px) * CDIM + c0 + h * 16;
    *(uint4*)dst = u0;
    *(uint4*)(dst + 8) = u1;
}

// ============================ MFMA conv v2: 2-phase pipelined, dedup weights ======
// R9 structure + LDS shrink (PXTP=130, ~50.8KB dbuf) + launch_bounds(256,3)
// -> 3 blocks/CU for more cross-block overlap of the barrier drain.
template <int CIN, int COUT, int BM, int BN, bool RELU>
__global__ __launch_bounds__(256, 3) void convmf2_k(const unsigned short* __restrict__ Xt,
                                                    const unsigned short* __restrict__ Wt,
                                                    const float* __restrict__ bias,
                                                    unsigned short* __restrict__ Yt,
                                                    const unsigned short* __restrict__ zp) {
    constexpr int WM = BM / 4;
    constexpr int FM = WM / 16;
    constexpr int FN = BN / 16;
    constexpr int PXT = BN + 2;
    constexpr int PXTP = BN + 2;            // 130: g-group bank phases {0,8,16,24}
    constexpr int NCH = 12 * PXTP;          // 1560 chunks of 16B
    constexpr int NCB = CIN / 32;
    constexpr int TPR = WDIM / BN;          // 2
    constexpr int NBX = HDIM * TPR;         // 512 pixel tiles
    constexpr int PER = NBX / 8;            // 64 pixel tiles per XCD
    // +512 shorts (64 chunks) pad per buffer: partial-wave DMA lanes beyond NCH are
    // exec-masked (no write), pad is insurance for dest-range validity.
    __shared__ unsigned short s_tile[2][NCH * 8 + 512];

    const int tid = threadIdx.x;
    const int ln = tid & 63, wid = tid >> 6;
    const int ln15 = ln & 15, g = ln >> 4;

    // XCD-aware decode (bijective: blocks b = xcd + 8*k, k in [0, PER*GRIDY))
    const int b = blockIdx.x;
    const int xcd = b & 7;
    const int k = b >> 3;
    const int xt = xcd * PER + (k % PER);   // pixel tile [0, NBX)
    const int yt = k / PER;                 // ocb index [0, GRIDY)

    const int y0 = xt / TPR;
    const int x0 = (xt % TPR) * BN;
    const int ocb = yt * BM;

    auto stage = [&](int buf, int cb) {
#pragma unroll
        for (int c0 = 0; c0 < NCH; c0 += 256) {
            if (c0 + wid * 64 < NCH) {      // wave-uniform: skip fully-OOB waves
                int c = c0 + tid;
                int grow = c / PXTP;
                int px = c - grow * PXTP;
                int ky = grow >> 2, gg = grow & 3;
                int y = y0 + ky - 1;
                int x = x0 - 1 + px;
                bool ok = (c < NCH) && (px < PXT) && ((unsigned)y < HDIM) && ((unsigned)x < WDIM);
                if (c < NCH) {
                    const unsigned short* src = ok
                        ? Xt + (size_t)(y * WDIM + x) * CIN + cb * 32 + gg * 8
                        : zp;
                    gload_lds16(src, &s_tile[buf][(size_t)(c0 + wid * 64) * 8]);
                }
            }
        }
    };

    f32x4 acc[FM][FN];
#pragma unroll
    for (int i = 0; i < FM; ++i)
#pragma unroll
        for (int j = 0; j < FN; ++j) acc[i][j] = f32x4{0.f, 0.f, 0.f, 0.f};

    const unsigned short* wfb = Wt + (size_t)(ocb + wid * WM + ln15) * 32 + g * 8;

    stage(0, 0);

    for (int cb = 0; cb < NCB; ++cb) {
        const int buf = cb & 1;
        __syncthreads();
        bf16x8 wreg[9][FM];
#pragma unroll
        for (int tap = 0; tap < 9; ++tap)
#pragma unroll
            for (int mf = 0; mf < FM; ++mf)
                wreg[tap][mf] = *(const bf16x8*)(wfb + (size_t)((cb * 9 + tap) * COUT + mf * 16) * 32);
        if (cb + 1 < NCB) stage(buf ^ 1, cb + 1);
        const unsigned short* st = &s_tile[buf][0];
#pragma unroll
        for (int tap = 0; tap < 9; ++tap) {
            const int ky = tap / 3, kx = tap - ky * 3;
            bf16x8 bfr[FN];
#pragma unroll
            for (int nf = 0; nf < FN; ++nf) {
                int slot = (ky * 4 + g) * PXTP + kx + nf * 16 + ln15;
                bfr[nf] = *(const bf16x8*)&st[(size_t)slot * 8];
            }
#pragma unroll
            for (int mf = 0; mf < FM; ++mf)
#pragma unroll
                for (int nf = 0; nf < FN; ++nf)
                    acc[mf][nf] = __builtin_amdgcn_mfma_f32_16x16x32_bf16(wreg[tap][mf], bfr[nf], acc[mf][nf], 0, 0, 0);
        }
    }

    const int p0 = y0 * WDIM + x0;
#pragma unroll
    for (int nf = 0; nf < FN; ++nf) {
        const size_t p = (size_t)p0 + nf * 16 + ln15;
#pragma unroll
        for (int mf = 0; mf < FM; ++mf) {
            const int oc0 = ocb + wid * WM + mf * 16 + g * 4;
            const float4 bi = *(const float4*)(bias + oc0);
            f32x4 v = acc[mf][nf];
            float r0 = v[0] + bi.x, r1 = v[1] + bi.y, r2 = v[2] + bi.z, r3 = v[3] + bi.w;
            if (RELU) {
                r0 = fmaxf(r0, 0.f); r1 = fmaxf(r1, 0.f);
                r2 = fmaxf(r2, 0.f); r3 = fmaxf(r3, 0.f);
            }
            unsigned lo = (unsigned)f2bf(r0) | ((unsigned)f2bf(r1) << 16);
            unsigned hi = (unsigned)f2bf(r2) | ((unsigned)f2bf(r3) << 16);
            *(uint2*)(Yt + p * COUT + oc0) = uint2{lo, hi};
        }
    }
}

// ============================ MFMA conv v1 (conv3, f32 out) ============================
template <int CIN, int COUT, int BM, int BN, int WM, int WN, bool RELU>
__global__ __launch_bounds__(256, 2) void convmf_k(const unsigned short* __restrict__ Xt,
                                                   const unsigned short* __restrict__ Wt,
                                                   const float* __restrict__ bias,
                                                   float* __restrict__ Yf,
                                                   const unsigned short* __restrict__ zp) {
    constexpr int WAVES_N = BN / WN;
    constexpr int FM = WM / 16, FN = WN / 16;
    constexpr int PXT = BN + 2;
    constexpr int PXTP = BN + 6;
    constexpr int NCH = 12 * PXTP;
    constexpr int NCHP = (NCH + 255) & ~255;
    __shared__ unsigned short s_tile[NCHP * 8];

    const int tid = threadIdx.x;
    const int ln = tid & 63, wid = tid >> 6;
    const int ln15 = ln & 15, g = ln >> 4;
    const int wm_i = wid / WAVES_N, wn_i = wid % WAVES_N;

    // XCD swizzle (grid.x divisible by 8)
    const int per = gridDim.x >> 3;
    const int tile = (blockIdx.x & 7) * per + (blockIdx.x >> 3);

    constexpr int TPR = WDIM / BN;
    const int y0 = tile / TPR;
    const int x0 = (tile % TPR) * BN;
    const int ocb = blockIdx.y * BM;

    f32x4 acc[FM][FN];
#pragma unroll
    for (int i = 0; i < FM; ++i)
#pragma unroll
        for (int j = 0; j < FN; ++j) acc[i][j] = f32x4{0.f, 0.f, 0.f, 0.f};

    const unsigned short* wfb = Wt + (size_t)(ocb + wm_i * WM + ln15) * 32 + g * 8;

    for (int cb = 0; cb < CIN / 32; ++cb) {
        __syncthreads();
        for (int c0 = 0; c0 < NCH; c0 += 256) {
            int c = c0 + tid;
            if (c < NCH) {
                int grow = c / PXTP;
                int px = c - grow * PXTP;
                int ky = grow >> 2, gg = grow & 3;
                int y = y0 + ky - 1;
                int x = x0 - 1 + px;
                bool ok = (px < PXT) && ((unsigned)y < HDIM) && ((unsigned)x < WDIM);
                const unsigned short* src = ok
                    ? Xt + (size_t)(y * WDIM + x) * CIN + cb * 32 + gg * 8
                    : zp;
                gload_lds16(src, &s_tile[(size_t)(c0 + wid * 64) * 8]);
            }
        }
        bf16x8 wreg[9][FM];
#pragma unroll
        for (int tap = 0; tap < 9; ++tap)
#pragma unroll
            for (int mf = 0; mf < FM; ++mf)
                wreg[tap][mf] = *(const bf16x8*)(wfb + (size_t)((cb * 9 + tap) * COUT + mf * 16) * 32);
        __syncthreads();
#pragma unroll
        for (int tap = 0; tap < 9; ++tap) {
            const int ky = tap / 3, kx = tap - ky * 3;
            bf16x8 b[FN];
#pragma unroll
            for (int nf = 0; nf < FN; ++nf) {
                int slot = (ky * 4 + g) * PXTP + kx + wn_i * WN + nf * 16 + ln15;
                b[nf] = *(const bf16x8*)&s_tile[(size_t)slot * 8];
            }
#pragma unroll
            for (int mf = 0; mf < FM; ++mf)
#pragma unroll
                for (int nf = 0; nf < FN; ++nf)
                    acc[mf][nf] = __builtin_amdgcn_mfma_f32_16x16x32_bf16(wreg[tap][mf], b[nf], acc[mf][nf], 0, 0, 0);
        }
    }

    const int p0 = y0 * WDIM + x0;
#pragma unroll
    for (int nf = 0; nf < FN; ++nf) {
        const size_t p = (size_t)p0 + wn_i * WN + nf * 16 + ln15;
#pragma unroll
        for (int mf = 0; mf < FM; ++mf) {
            const int oc0 = ocb + wm_i * WM + mf * 16 + g * 4;
            const float4 bi = *(const float4*)(bias + oc0);
            f32x4 v = acc[mf][nf];
            float r0 = v[0] + bi.x, r1 = v[1] + bi.y, r2 = v[2] + bi.z, r3 = v[3] + bi.w;
            if (RELU) {
                r0 = fmaxf(r0, 0.f); r1 = fmaxf(r1, 0.f);
                r2 = fmaxf(r2, 0.f); r3 = fmaxf(r3, 0.f);
            }
            Yf[(size_t)(oc0 + 0) * HW + p] = r0;
            Yf[(size_t)(oc0 + 1) * HW + p] = r1;
            Yf[(size_t)(oc0 + 2) * HW + p] = r2;
            Yf[(size_t)(oc0 + 3) * HW + p] = r3;
        }
    }
}

// ============================ compress as MFMA GEMM from Xt ============================
__global__ __launch_bounds__(256, 2) void ccv_gemm_k(const unsigned short* __restrict__ Xt,
                                                     const unsigned short* __restrict__ wc,
                                                     const float* __restrict__ cbias,
                                                     float* __restrict__ ccv) {
    __shared__ unsigned short s_t[1024 * 8];
    const int tid = threadIdx.x;
    const int ln = tid & 63, wid = tid >> 6;
    const int ln15 = ln & 15, g = ln >> 4;
    const int per = gridDim.x >> 3;
    const int tile = (blockIdx.x & 7) * per + (blockIdx.x >> 3);
    const int p0 = tile * 256;

    f32x4 acc[2][4];
#pragma unroll
    for (int i = 0; i < 2; ++i)
#pragma unroll
        for (int j = 0; j < 4; ++j) acc[i][j] = f32x4{0.f, 0.f, 0.f, 0.f};

    for (int cb = 0; cb < 16; ++cb) {
        __syncthreads();
#pragma unroll
        for (int pass = 0; pass < 4; ++pass) {
            int c = pass * 256 + tid;
            int gg = c >> 8, px = c & 255;
            const unsigned short* src = Xt + (size_t)(p0 + px) * CDIM + cb * 32 + gg * 8;
            gload_lds16(src, &s_t[(size_t)c * 8]);
        }
        bf16x8 a[2];
#pragma unroll
        for (int mf = 0; mf < 2; ++mf)
            a[mf] = *(const bf16x8*)(wc + (size_t)((cb * 32 + mf * 16 + ln15) * 32) + g * 8);
        __syncthreads();
        bf16x8 b[4];
#pragma unroll
        for (int nf = 0; nf < 4; ++nf) {
            int slot = g * 256 + wid * 64 + nf * 16 + ln15;
            b[nf] = *(const bf16x8*)&s_t[(size_t)slot * 8];
        }
#pragma unroll
        for (int mf = 0; mf < 2; ++mf)
#pragma unroll
            for (int nf = 0; nf < 4; ++nf)
                acc[mf][nf] = __builtin_amdgcn_mfma_f32_16x16x32_bf16(a[mf], b[nf], acc[mf][nf], 0, 0, 0);
    }
#pragma unroll
    for (int nf = 0; nf < 4; ++nf) {
        const size_t p = (size_t)p0 + wid * 64 + nf * 16 + ln15;
#pragma unroll
        for (int mf = 0; mf < 2; ++mf) {
            const int oc0 = mf * 16 + g * 4;
            const float4 bi = *(const float4*)(cbias + oc0);
            f32x4 v = acc[mf][nf];
            ccv[(size_t)(oc0 + 0) * HW + p] = v[0] + bi.x;
            ccv[(size_t)(oc0 + 1) * HW + p] = v[1] + bi.y;
            ccv[(size_t)(oc0 + 2) * HW + p] = v[2] + bi.z;
            ccv[(size_t)(oc0 + 3) * HW + p] = v[3] + bi.w;
        }
    }
}

// ============================ cov / fc / combine ============================

__global__ __launch_bounds__(256) void cov_accum_k(const float* __restrict__ f,
                                                   const unsigned char* __restrict__ code,
                                                   float* __restrict__ covraw) {
    constexpr int PCH = 256;
    __shared__ float s_f[32][PCH + 1];
    const int i = blockIdx.y;
    const int p0 = blockIdx.x * PCH;
    const int t = threadIdx.x;
    for (int e = t; e < 32 * PCH; e += 256) {
        int row = e >> 8, col = e & (PCH - 1);
        int p = p0 + col;
        float m = ((code[p] >> i) & 1u) ? 1.f : 0.f;
        s_f[row][col] = f[(size_t)row * HW + p] * m;
    }
    __syncthreads();
    const int a = t >> 3;
    const int b0 = (t & 7) * 4;
    float a0 = 0.f, a1 = 0.f, a2 = 0.f, a3 = 0.f;
    for (int p = 0; p < PCH; ++p) {
        float va = s_f[a][p];
        a0 = fmaf(va, s_f[b0 + 0][p], a0);
        a1 = fmaf(va, s_f[b0 + 1][p], a1);
        a2 = fmaf(va, s_f[b0 + 2][p], a2);
        a3 = fmaf(va, s_f[b0 + 3][p], a3);
    }
    float* dst = covraw + i * 1024 + a * 32 + b0;
    atomicAdd(dst + 0, a0);
    atomicAdd(dst + 1, a1);
    atomicAdd(dst + 2, a2);
    atomicAdd(dst + 3, a3);
}

__global__ __launch_bounds__(256) void fc_k(const float* __restrict__ fcw,
                                            const float* __restrict__ fcb,
                                            const float* __restrict__ covraw,
                                            const int* __restrict__ cnt,
                                            float* __restrict__ mats) {
    const int i = blockIdx.y;
    const int wv = threadIdx.x >> 6;
    const int lane = threadIdx.x & 63;
    const int r = blockIdx.x * 4 + wv;
    const float inv = 1.f / fmaxf((float)cnt[i], 1.f);
    float acc = 0.f;
    for (int q = lane; q < 1024; q += 64)
        acc = fmaf(fcw[r * 1024 + q], covraw[i * 1024 + q] * inv, acc);
    for (int off = 32; off; off >>= 1) acc += __shfl_down(acc, off);
    if (lane == 0) mats[i * 1024 + r] = acc + fcb[r];
}

__global__ __launch_bounds__(256) void prep_small_k(const float* __restrict__ sMats,
                                                    const float* __restrict__ cMats,
                                                    const float* __restrict__ unzip_b,
                                                    const float* __restrict__ smean5,
                                                    int n,
                                                    float* __restrict__ tm5,
                                                    float* __restrict__ B5) {
    int t = blockIdx.x * 256 + threadIdx.x;
    if (t < 5 * 1024) {
        int i = t >> 10, rc = t & 1023, r = rc >> 5, c = rc & 31;
        float v;
        if (i < n) {
            float s = 0.f;
            for (int k = 0; k < 32; ++k)
                s = fmaf(sMats[i * 1024 + r * 32 + k], cMats[i * 1024 + k * 32 + c], s);
            v = s;
        } else {
            v = (r == c) ? 1.f : 0.f;
        }
        tm5[t] = v;
    } else if (t < 5 * 1024 + 5 * 512) {
        int u = t - 5 * 1024;
        int i = u >> 9, c = u & 511;
        B5[u] = unzip_b[c] + smean5[i * CDIM + c];
    }
}

__global__ __launch_bounds__(256) void final_k(const float* __restrict__ ccv,
                                               const signed char* __restrict__ fidx,
                                               const float* __restrict__ tm5,
                                               const float* __restrict__ B5,
                                               const float* __restrict__ uw,
                                               float* __restrict__ out) {
    __shared__ float s_tm[5 * 1032];
    __shared__ float s_B[5 * 520];
    const int t = threadIdx.x;
    for (int e = t; e < 5 * 1024; e += 256) {
        int i = e >> 10, rc = e & 1023;
        s_tm[i * 1032 + rc] = tm5[e];
    }
    for (int e = t; e < 5 * 512; e += 256) {
        int i = e >> 9, c = e & 511;
        s_B[i * 520 + c] = B5[e];
    }
    __syncthreads();
    const int p = blockIdx.x * 256 + t;
    const int id = fidx[p];
    float v[32];
#pragma unroll
    for (int k = 0; k < 32; ++k) v[k] = ccv[(size_t)k * HW + p];
    float tv[32];
#pragma unroll
    for (int r = 0; r < 32; ++r) {
        float s = 0.f;
#pragma unroll
        for (int k = 0; k < 32; ++k)
            s = fmaf(s_tm[id * 1032 + r * 32 + k], v[k], s);
        tv[r] = s;
    }
    for (int c = 0; c < CDIM; ++c) {
        float s = s_B[id * 520 + c];
#pragma unroll
        for (int k = 0; k < 32; ++k)
            s = fmaf(uw[c * 32 + k], tv[k], s);
        out[(size_t)c * HW + p] = s;
    }
}

// ============================ launch ============================

extern "C" void kernel_launch(void* const* d_in, const int* in_sizes, int n_in,
                              void* d_out, int out_size, void* d_ws, size_t ws_size,
                              hipStream_t stream) {
    const float* cF = (const float*)d_in[0];
    const float* sF = (const float*)d_in[1];
    const int* cmasks = (const int*)d_in[2];
    const int* smasks = (const int*)d_in[3];
    const float* snet_w1 = (const float*)d_in[4];
    const float* snet_b1 = (const float*)d_in[5];
    const float* snet_w2 = (const float*)d_in[6];
    const float* snet_b2 = (const float*)d_in[7];
    const float* snet_w3 = (const float*)d_in[8];
    const float* snet_b3 = (const float*)d_in[9];
    const float* snet_fcw = (const float*)d_in[10];
    const float* snet_fcb = (const float*)d_in[11];
    const float* cnet_w1 = (const float*)d_in[12];
    const float* cnet_b1 = (const float*)d_in[13];
    const float* cnet_w2 = (const float*)d_in[14];
    const float* cnet_b2 = (const float*)d_in[15];
    const float* cnet_w3 = (const float*)d_in[16];
    const float* cnet_b3 = (const float*)d_in[17];
    const float* cnet_fcw = (const float*)d_in[18];
    const float* cnet_fcb = (const float*)d_in[19];
    const float* compress_w = (const float*)d_in[20];
    const float* compress_b = (const float*)d_in[21];
    const float* unzip_w = (const float*)d_in[22];
    const float* unzip_b = (const float*)d_in[23];
    float* out = (float*)d_out;

    int nmC = in_sizes[2] / HW;
    int nmS = in_sizes[3] / HW;
    int n = nmC < nmS ? nmC : nmS;
    if (n > 4) n = 4;

    char* ws = (char*)d_ws;
    size_t off = 0;
    auto alloc = [&](size_t bytes) {
        size_t o = off;
        off += (bytes + 255) & ~(size_t)255;
        return o;
    };
    char* regA = ws + alloc((size_t)HW * 512 * 2);   // Xt / Y2
    char* regB = ws + alloc((size_t)HW * 256 * 2);   // Y1 / fbuf
    float* ccv  = (float*)(ws + alloc((size_t)32 * HW * 4));
    unsigned short* Wt1s = (unsigned short*)(ws + alloc((size_t)9 * 256 * 512 * 2));
    unsigned short* Wt2s = (unsigned short*)(ws + alloc((size_t)9 * 128 * 256 * 2));
    unsigned short* Wt3s = (unsigned short*)(ws + alloc((size_t)9 * 32 * 128 * 2));
    unsigned short* Wt1c = (unsigned short*)(ws + alloc((size_t)9 * 256 * 512 * 2));
    unsigned short* Wt2c = (unsigned short*)(ws + alloc((size_t)9 * 128 * 256 * 2));
    unsigned short* Wt3c = (unsigned short*)(ws + alloc((size_t)9 * 32 * 128 * 2));
    unsigned short* Wc  = (unsigned short*)(ws + alloc((size_t)32 * 512 * 2));
    unsigned char* ccode = (unsigned char*)(ws + alloc(HW));
    unsigned char* scode = (unsigned char*)(ws + alloc(HW));
    signed char* cidx = (signed char*)(ws + alloc(HW));
    signed char* sidx = (signed char*)(ws + alloc(HW));
    signed char* fidx = (signed char*)(ws + alloc(HW));
    int*   cnt    = (int*)(ws + alloc(8 * 4));
    float* cmean5 = (float*)(ws + alloc(5 * CDIM * 4));
    float* smean5 = (float*)(ws + alloc(5 * CDIM * 4));
    float* covraw = (float*)(ws + alloc(8 * 1024 * 4));
    float* sMats  = (float*)(ws + alloc(4 * 1024 * 4));
    float* cMats  = (float*)(ws + alloc(4 * 1024 * 4));
    float* tm5    = (float*)(ws + alloc(5 * 1024 * 4));
    float* B5     = (float*)(ws + alloc(5 * 512 * 4));
    float* zpf    = (float*)(ws + alloc(256));
    (void)ws_size; (void)n_in; (void)out_size;

    unsigned short* Xt = (unsigned short*)regA;
    unsigned short* Y2 = (unsigned short*)regA;   // overwrites Xt only at conv2 (Xt dead)
    unsigned short* Y1 = (unsigned short*)regB;
    float*          fbuf = (float*)regB;
    const unsigned short* zp = (const unsigned short*)zpf;

    // ---- stage 0: fused prep (zero + all weight transforms) + masks/means/idx ----
    prep_all_k<<<11905, 256, 0, stream>>>(cnt, covraw, zpf, compress_w, Wc,
                                          snet_w1, Wt1s, snet_w2, Wt2s, snet_w3, Wt3s,
                                          cnet_w1, Wt1c, cnet_w2, Wt2c, cnet_w3, Wt3c);
    pack_masks_k<<<HW / 256, 256, 0, stream>>>(cmasks, smasks, n, ccode, scode, cnt);
    masked_means_k<<<2 * CDIM, 256, 0, stream>>>(cF, sF, ccode, scode, cnt, cmean5, smean5);
    idx_maps_k<<<HW / 256, 256, 0, stream>>>(ccode, scode, cnt, n, cidx, sidx, fidx);

    // ---- snet ----
    trans_in_k<<<dim3(HW / 64, 8), 256, 0, stream>>>(sF, smean5, sidx, Xt);
    convmf2_k<512, 256, 128, 128, true ><<<1024, 256, 0, stream>>>(Xt, Wt1s, snet_b1, Y1, zp);
    convmf2_k<256, 128, 128, 128, true ><<<512, 256, 0, stream>>>(Y1, Wt2s, snet_b2, Y2, zp);
    convmf_k<128, 32,  32,  256, 32, 64, false><<<dim3(256, 1), 256, 0, stream>>>(Y2, Wt3s, snet_b3, fbuf, zp);
    cov_accum_k<<<dim3(HW / 256, n), 256, 0, stream>>>(fbuf, scode, covraw);
    fc_k<<<dim3(256, n), 256, 0, stream>>>(snet_fcw, snet_fcb, covraw, cnt + 4, sMats);

    // ---- cnet ----
    trans_in_k<<<dim3(HW / 64, 8), 256, 0, stream>>>(cF, cmean5, cidx, Xt);
    ccv_gemm_k<<<HW / 256, 256, 0, stream>>>(Xt, Wc, compress_b, ccv);   // while Xt alive
    convmf2_k<512, 256, 128, 128, true ><<<1024, 256, 0, stream>>>(Xt, Wt1c, cnet_b1, Y1, zp);
    convmf2_k<256, 128, 128, 128, true ><<<512, 256, 0, stream>>>(Y1, Wt2c, cnet_b2, Y2, zp);
    convmf_k<128, 32,  32,  256, 32, 64, false><<<dim3(256, 1), 256, 0, stream>>>(Y2, Wt3c, cnet_b3, fbuf, zp);
    cov_accum_k<<<dim3(HW / 256, n), 256, 0, stream>>>(fbuf, ccode, covraw + 4 * 1024);
    fc_k<<<dim3(256, n), 256, 0, stream>>>(cnet_fcw, cnet_fcb, covraw + 4 * 1024, cnt, cMats);

    // ---- combine ----
    prep_small_k<<<30, 256, 0, stream>>>(sMats, cMats, unzip_b, smean5, n, tm5, B5);
    final_k<<<HW / 256, 256, 0, stream>>>(ccv, fidx, tm5, B5, unzip_w, out);
}

// Round 11
// 962.513 us; speedup vs baseline: 1.2925x; 1.2925x over previous
//
#include <hip/hip_runtime.h>

#define HDIM 256
#define WDIM 256
#define HW   65536
#define CDIM 512

using bf16x8 = __attribute__((ext_vector_type(8))) short;
using f32x4  = __attribute__((ext_vector_type(4))) float;

__device__ __forceinline__ unsigned short f2bf(float f) {
    unsigned u = __builtin_bit_cast(unsigned, f);
    u += 0x7FFFu + ((u >> 16) & 1u);          // RNE
    return (unsigned short)(u >> 16);
}

__device__ __forceinline__ void gload_lds16(const void* g, void* l) {
    __builtin_amdgcn_global_load_lds((const __attribute__((address_space(1))) unsigned int*)g,
                                     (__attribute__((address_space(3))) unsigned int*)l, 16, 0, 0);
}

// ============================ fused prep (zero + all weight transforms) ============

__device__ __forceinline__ void wtrans_one(const float* __restrict__ w,
                                           unsigned short* __restrict__ wt,
                                           int COUT, int CIN, int t) {
    int oc = t / (CIN * 9);
    int rem = t - oc * (CIN * 9);
    int ci = rem / 9;
    int tap = rem - ci * 9;
    wt[(size_t)(((ci >> 5) * 9 + tap) * COUT + oc) * 32 + (ci & 31)] = f2bf(w[t]);
}

__global__ __launch_bounds__(256) void prep_all_k(int* __restrict__ cnt,
                                                  float* __restrict__ covraw,
                                                  float* __restrict__ zp,
                                                  const float* __restrict__ cw, unsigned short* __restrict__ wc,
                                                  const float* __restrict__ s1, unsigned short* __restrict__ W1s,
                                                  const float* __restrict__ s2, unsigned short* __restrict__ W2s,
                                                  const float* __restrict__ s3, unsigned short* __restrict__ W3s,
                                                  const float* __restrict__ c1, unsigned short* __restrict__ W1c,
                                                  const float* __restrict__ c2, unsigned short* __restrict__ W2c,
                                                  const float* __restrict__ c3, unsigned short* __restrict__ W3c) {
    int t = blockIdx.x * 256 + threadIdx.x;
    if (t < 8264) {
        if (t < 8) cnt[t] = 0;
        else if (t < 8200) covraw[t - 8] = 0.f;
        else if (t < 8264) zp[t - 8200] = 0.f;
        return;
    }
    t -= 8264;
    if (t < 16384) {                       // compress_w -> wc[ci/32][oc][ci%32]
        int oc = t >> 9, ci = t & 511;
        wc[(size_t)((ci >> 5) * 32 + oc) * 32 + (ci & 31)] = f2bf(cw[t]);
        return;
    }
    t -= 16384;
    if (t < 1179648) { wtrans_one(s1, W1s, 256, 512, t); return; }
    t -= 1179648;
    if (t < 294912)  { wtrans_one(s2, W2s, 128, 256, t); return; }
    t -= 294912;
    if (t < 36864)   { wtrans_one(s3, W3s, 32, 128, t); return; }
    t -= 36864;
    if (t < 1179648) { wtrans_one(c1, W1c, 256, 512, t); return; }
    t -= 1179648;
    if (t < 294912)  { wtrans_one(c2, W2c, 128, 256, t); return; }
    t -= 294912;
    if (t < 36864)   { wtrans_one(c3, W3c, 32, 128, t); return; }
}

// ============================ small kernels ============================

__global__ __launch_bounds__(256) void pack_masks_k(const int* __restrict__ cm,
                                                    const int* __restrict__ sm,
                                                    int n,
                                                    unsigned char* __restrict__ ccode,
                                                    unsigned char* __restrict__ scode,
                                                    int* __restrict__ cnt) {
    int p = blockIdx.x * 256 + threadIdx.x;
    unsigned cc = 0, sc = 0;
    for (int i = 0; i < n; ++i) {
        if (cm[i * HW + p] != 0) cc |= (1u << i);
        if (sm[i * HW + p] != 0) sc |= (1u << i);
    }
    ccode[p] = (unsigned char)cc;
    scode[p] = (unsigned char)sc;
    int lane = threadIdx.x & 63;
    for (int i = 0; i < n; ++i) {
        unsigned long long bc = __ballot((cc >> i) & 1);
        unsigned long long bs = __ballot((sc >> i) & 1);
        if (lane == 0) {
            atomicAdd(&cnt[i],     (int)__popcll(bc));
            atomicAdd(&cnt[4 + i], (int)__popcll(bs));
        }
    }
}

// vectorized: float4 pixel loads + packed uint code loads
__global__ __launch_bounds__(256) void masked_means_k(const float* __restrict__ cF,
                                                      const float* __restrict__ sF,
                                                      const unsigned char* __restrict__ ccode,
                                                      const unsigned char* __restrict__ scode,
                                                      const int* __restrict__ cnt,
                                                      float* __restrict__ cmean5,
                                                      float* __restrict__ smean5) {
    int b = blockIdx.x;
    const float* x; const unsigned char* code; const int* cn; float* mout;
    if (b < CDIM) { x = cF; code = ccode; cn = cnt;     mout = cmean5; }
    else          { x = sF; code = scode; cn = cnt + 4; mout = smean5; b -= CDIM; }
    const int c = b;
    const int t = threadIdx.x;
    const float4* x4 = (const float4*)(x + (size_t)c * HW);
    const unsigned* cd4 = (const unsigned*)code;
    float s0 = 0.f, s1 = 0.f, s2 = 0.f, s3 = 0.f;
    for (int i = t; i < HW / 4; i += 256) {
        float4 v = x4[i];
        unsigned cd = cd4[i];
        float vv;
        vv = v.x;
        if (cd & 0x01u) s0 += vv;
        if (cd & 0x02u) s1 += vv;
        if (cd & 0x04u) s2 += vv;
        if (cd & 0x08u) s3 += vv;
        vv = v.y;
        if (cd & 0x0100u) s0 += vv;
        if (cd & 0x0200u) s1 += vv;
        if (cd & 0x0400u) s2 += vv;
        if (cd & 0x0800u) s3 += vv;
        vv = v.z;
        if (cd & 0x010000u) s0 += vv;
        if (cd & 0x020000u) s1 += vv;
        if (cd & 0x040000u) s2 += vv;
        if (cd & 0x080000u) s3 += vv;
        vv = v.w;
        if (cd & 0x01000000u) s0 += vv;
        if (cd & 0x02000000u) s1 += vv;
        if (cd & 0x04000000u) s2 += vv;
        if (cd & 0x08000000u) s3 += vv;
    }
    __shared__ float red[4][256];
    red[0][t] = s0; red[1][t] = s1; red[2][t] = s2; red[3][t] = s3;
    __syncthreads();
    for (int off = 128; off; off >>= 1) {
        if (t < off) {
            red[0][t] += red[0][t + off];
            red[1][t] += red[1][t + off];
            red[2][t] += red[2][t + off];
            red[3][t] += red[3][t + off];
        }
        __syncthreads();
    }
    if (t < 4) mout[t * CDIM + c] = red[t][0] / fmaxf((float)cn[t], 1.f);
    if (t == 4) mout[4 * CDIM + c] = 0.f;
}

__global__ __launch_bounds__(256) void idx_maps_k(const unsigned char* __restrict__ ccode,
                                                  const unsigned char* __restrict__ scode,
                                                  const int* __restrict__ cnt, int n,
                                                  signed char* __restrict__ cidx,
                                                  signed char* __restrict__ sidx,
                                                  signed char* __restrict__ fidx) {
    int p = blockIdx.x * 256 + threadIdx.x;
    int cc = ccode[p], sc = scode[p];
    int ci = 4, si = 4, fi = 4;
    for (int i = 0; i < n; ++i) {
        bool cv = cnt[i] >= 10;
        bool sv = cnt[4 + i] >= 10;
        if (((cc >> i) & 1) && cv) ci = i;
        if (((sc >> i) & 1) && sv) si = i;
        if (((cc >> i) & 1) && cv && sv) fi = i;
    }
    cidx[p] = (signed char)ci;
    sidx[p] = (signed char)si;
    fidx[p] = (signed char)fi;
}

// X[512][HW] f32 -> Xt[HW][512] bf16, fused mean-sub (float4 loads, pair-packed)
__global__ __launch_bounds__(256) void trans_in_k(const float* __restrict__ X,
                                                  const float* __restrict__ mean5,
                                                  const signed char* __restrict__ idx5,
                                                  unsigned short* __restrict__ Xt) {
    __shared__ unsigned s32[64 * 33];     // [px][32 u32 + 1 pad]
    const int tid = threadIdx.x;
    const int p0 = blockIdx.x * 64;
    const int c0 = blockIdx.y * 64;
    const int cpair = tid >> 3;
    const int q = tid & 7;
    const int ch0 = c0 + cpair * 2;
    const float* X0 = X + (size_t)ch0 * HW;
    const float* X1 = X0 + HW;
#pragma unroll
    for (int k = 0; k < 2; ++k) {
        int px0 = (q + k * 8) * 4;
        float4 va = *(const float4*)(X0 + p0 + px0);
        float4 vb = *(const float4*)(X1 + p0 + px0);
        int id4 = *(const int*)(idx5 + p0 + px0);
        float a[4] = {va.x, va.y, va.z, va.w};
        float b[4] = {vb.x, vb.y, vb.z, vb.w};
#pragma unroll
        for (int j = 0; j < 4; ++j) {
            int id = (id4 >> (8 * j)) & 0xFF;
            const float* mr = mean5 + id * CDIM;
            unsigned u = (unsigned)f2bf(a[j] - mr[ch0])
                       | ((unsigned)f2bf(b[j] - mr[ch0 + 1]) << 16);
            s32[(px0 + j) * 33 + cpair] = u;
        }
    }
    __syncthreads();
    const int px = tid >> 2, h = tid & 3;
    const unsigned* rp = &s32[px * 33 + h * 8];
    uint4 u0 = *(const uint4*)(rp);
    uint4 u1 = *(const uint4*)(rp + 4);
    unsigned short* dst = Xt + (size_t)(p0 + px) * CDIM + c0 + h * 16;
    *(uint4*)dst = u0;
    *(uint4*)(dst + 8) = u1;
}

// ============================ MFMA conv v2: 2-phase pipelined, dedup weights ======
// R9-proven codegen (launch_bounds(256,2), VGPR=128, no spill) + compact LDS
// (PXTP=130 -> 52.2KB total) so occupancy rises to 3 blocks/CU via the LDS
// limiter without constraining the register allocator.
template <int CIN, int COUT, int BM, int BN, bool RELU>
__global__ __launch_bounds__(256, 2) void convmf2_k(const unsigned short* __restrict__ Xt,
                                                    const unsigned short* __restrict__ Wt,
                                                    const float* __restrict__ bias,
                                                    unsigned short* __restrict__ Yt,
                                                    const unsigned short* __restrict__ zp) {
    constexpr int WM = BM / 4;
    constexpr int FM = WM / 16;
    constexpr int FN = BN / 16;
    constexpr int PXT = BN + 2;
    constexpr int PXTP = BN + 2;            // 130: g-group bank phases {0,8,16,24}
    constexpr int NCH = 12 * PXTP;          // 1560 chunks of 16B
    constexpr int NCB = CIN / 32;
    constexpr int TPR = WDIM / BN;          // 2
    constexpr int NBX = HDIM * TPR;         // 512 pixel tiles
    constexpr int PER = NBX / 8;            // 64 pixel tiles per XCD
    __shared__ unsigned short s_tile[2][NCH * 8 + 512];

    const int tid = threadIdx.x;
    const int ln = tid & 63, wid = tid >> 6;
    const int ln15 = ln & 15, g = ln >> 4;

    // XCD-aware decode (bijective: blocks b = xcd + 8*k, k in [0, PER*GRIDY))
    const int b = blockIdx.x;
    const int xcd = b & 7;
    const int k = b >> 3;
    const int xt = xcd * PER + (k % PER);   // pixel tile [0, NBX)
    const int yt = k / PER;                 // ocb index [0, GRIDY)

    const int y0 = xt / TPR;
    const int x0 = (xt % TPR) * BN;
    const int ocb = yt * BM;

    auto stage = [&](int buf, int cb) {
#pragma unroll
        for (int c0 = 0; c0 < NCH; c0 += 256) {
            int c = c0 + tid;
            if (c < NCH) {
                int grow = c / PXTP;
                int px = c - grow * PXTP;
                int ky = grow >> 2, gg = grow & 3;
                int y = y0 + ky - 1;
                int x = x0 - 1 + px;
                bool ok = (px < PXT) && ((unsigned)y < HDIM) && ((unsigned)x < WDIM);
                const unsigned short* src = ok
                    ? Xt + (size_t)(y * WDIM + x) * CIN + cb * 32 + gg * 8
                    : zp;
                gload_lds16(src, &s_tile[buf][(size_t)(c0 + wid * 64) * 8]);
            }
        }
    };

    f32x4 acc[FM][FN];
#pragma unroll
    for (int i = 0; i < FM; ++i)
#pragma unroll
        for (int j = 0; j < FN; ++j) acc[i][j] = f32x4{0.f, 0.f, 0.f, 0.f};

    const unsigned short* wfb = Wt + (size_t)(ocb + wid * WM + ln15) * 32 + g * 8;

    stage(0, 0);

    for (int cb = 0; cb < NCB; ++cb) {
        const int buf = cb & 1;
        __syncthreads();
        bf16x8 wreg[9][FM];
#pragma unroll
        for (int tap = 0; tap < 9; ++tap)
#pragma unroll
            for (int mf = 0; mf < FM; ++mf)
                wreg[tap][mf] = *(const bf16x8*)(wfb + (size_t)((cb * 9 + tap) * COUT + mf * 16) * 32);
        if (cb + 1 < NCB) stage(buf ^ 1, cb + 1);
        const unsigned short* st = &s_tile[buf][0];
#pragma unroll
        for (int tap = 0; tap < 9; ++tap) {
            const int ky = tap / 3, kx = tap - ky * 3;
            bf16x8 bfr[FN];
#pragma unroll
            for (int nf = 0; nf < FN; ++nf) {
                int slot = (ky * 4 + g) * PXTP + kx + nf * 16 + ln15;
                bfr[nf] = *(const bf16x8*)&st[(size_t)slot * 8];
            }
#pragma unroll
            for (int mf = 0; mf < FM; ++mf)
#pragma unroll
                for (int nf = 0; nf < FN; ++nf)
                    acc[mf][nf] = __builtin_amdgcn_mfma_f32_16x16x32_bf16(wreg[tap][mf], bfr[nf], acc[mf][nf], 0, 0, 0);
        }
    }

    const int p0 = y0 * WDIM + x0;
#pragma unroll
    for (int nf = 0; nf < FN; ++nf) {
        const size_t p = (size_t)p0 + nf * 16 + ln15;
#pragma unroll
        for (int mf = 0; mf < FM; ++mf) {
            const int oc0 = ocb + wid * WM + mf * 16 + g * 4;
            const float4 bi = *(const float4*)(bias + oc0);
            f32x4 v = acc[mf][nf];
            float r0 = v[0] + bi.x, r1 = v[1] + bi.y, r2 = v[2] + bi.z, r3 = v[3] + bi.w;
            if (RELU) {
                r0 = fmaxf(r0, 0.f); r1 = fmaxf(r1, 0.f);
                r2 = fmaxf(r2, 0.f); r3 = fmaxf(r3, 0.f);
            }
            unsigned lo = (unsigned)f2bf(r0) | ((unsigned)f2bf(r1) << 16);
            unsigned hi = (unsigned)f2bf(r2) | ((unsigned)f2bf(r3) << 16);
            *(uint2*)(Yt + p * COUT + oc0) = uint2{lo, hi};
        }
    }
}

// ============================ MFMA conv v1 (conv3, f32 out) ============================
template <int CIN, int COUT, int BM, int BN, int WM, int WN, bool RELU>
__global__ __launch_bounds__(256, 2) void convmf_k(const unsigned short* __restrict__ Xt,
                                                   const unsigned short* __restrict__ Wt,
                                                   const float* __restrict__ bias,
                                                   float* __restrict__ Yf,
                                                   const unsigned short* __restrict__ zp) {
    constexpr int WAVES_N = BN / WN;
    constexpr int FM = WM / 16, FN = WN / 16;
    constexpr int PXT = BN + 2;
    constexpr int PXTP = BN + 6;
    constexpr int NCH = 12 * PXTP;
    constexpr int NCHP = (NCH + 255) & ~255;
    __shared__ unsigned short s_tile[NCHP * 8];

    const int tid = threadIdx.x;
    const int ln = tid & 63, wid = tid >> 6;
    const int ln15 = ln & 15, g = ln >> 4;
    const int wm_i = wid / WAVES_N, wn_i = wid % WAVES_N;

    // XCD swizzle (grid.x divisible by 8)
    const int per = gridDim.x >> 3;
    const int tile = (blockIdx.x & 7) * per + (blockIdx.x >> 3);

    constexpr int TPR = WDIM / BN;
    const int y0 = tile / TPR;
    const int x0 = (tile % TPR) * BN;
    const int ocb = blockIdx.y * BM;

    f32x4 acc[FM][FN];
#pragma unroll
    for (int i = 0; i < FM; ++i)
#pragma unroll
        for (int j = 0; j < FN; ++j) acc[i][j] = f32x4{0.f, 0.f, 0.f, 0.f};

    const unsigned short* wfb = Wt + (size_t)(ocb + wm_i * WM + ln15) * 32 + g * 8;

    for (int cb = 0; cb < CIN / 32; ++cb) {
        __syncthreads();
        for (int c0 = 0; c0 < NCH; c0 += 256) {
            int c = c0 + tid;
            if (c < NCH) {
                int grow = c / PXTP;
                int px = c - grow * PXTP;
                int ky = grow >> 2, gg = grow & 3;
                int y = y0 + ky - 1;
                int x = x0 - 1 + px;
                bool ok = (px < PXT) && ((unsigned)y < HDIM) && ((unsigned)x < WDIM);
                const unsigned short* src = ok
                    ? Xt + (size_t)(y * WDIM + x) * CIN + cb * 32 + gg * 8
                    : zp;
                gload_lds16(src, &s_tile[(size_t)(c0 + wid * 64) * 8]);
            }
        }
        bf16x8 wreg[9][FM];
#pragma unroll
        for (int tap = 0; tap < 9; ++tap)
#pragma unroll
            for (int mf = 0; mf < FM; ++mf)
                wreg[tap][mf] = *(const bf16x8*)(wfb + (size_t)((cb * 9 + tap) * COUT + mf * 16) * 32);
        __syncthreads();
#pragma unroll
        for (int tap = 0; tap < 9; ++tap) {
            const int ky = tap / 3, kx = tap - ky * 3;
            bf16x8 b[FN];
#pragma unroll
            for (int nf = 0; nf < FN; ++nf) {
                int slot = (ky * 4 + g) * PXTP + kx + wn_i * WN + nf * 16 + ln15;
                b[nf] = *(const bf16x8*)&s_tile[(size_t)slot * 8];
            }
#pragma unroll
            for (int mf = 0; mf < FM; ++mf)
#pragma unroll
                for (int nf = 0; nf < FN; ++nf)
                    acc[mf][nf] = __builtin_amdgcn_mfma_f32_16x16x32_bf16(wreg[tap][mf], b[nf], acc[mf][nf], 0, 0, 0);
        }
    }

    const int p0 = y0 * WDIM + x0;
#pragma unroll
    for (int nf = 0; nf < FN; ++nf) {
        const size_t p = (size_t)p0 + wn_i * WN + nf * 16 + ln15;
#pragma unroll
        for (int mf = 0; mf < FM; ++mf) {
            const int oc0 = ocb + wm_i * WM + mf * 16 + g * 4;
            const float4 bi = *(const float4*)(bias + oc0);
            f32x4 v = acc[mf][nf];
            float r0 = v[0] + bi.x, r1 = v[1] + bi.y, r2 = v[2] + bi.z, r3 = v[3] + bi.w;
            if (RELU) {
                r0 = fmaxf(r0, 0.f); r1 = fmaxf(r1, 0.f);
                r2 = fmaxf(r2, 0.f); r3 = fmaxf(r3, 0.f);
            }
            Yf[(size_t)(oc0 + 0) * HW + p] = r0;
            Yf[(size_t)(oc0 + 1) * HW + p] = r1;
            Yf[(size_t)(oc0 + 2) * HW + p] = r2;
            Yf[(size_t)(oc0 + 3) * HW + p] = r3;
        }
    }
}

// ============================ compress as MFMA GEMM from Xt ============================
__global__ __launch_bounds__(256, 2) void ccv_gemm_k(const unsigned short* __restrict__ Xt,
                                                     const unsigned short* __restrict__ wc,
                                                     const float* __restrict__ cbias,
                                                     float* __restrict__ ccv) {
    __shared__ unsigned short s_t[1024 * 8];
    const int tid = threadIdx.x;
    const int ln = tid & 63, wid = tid >> 6;
    const int ln15 = ln & 15, g = ln >> 4;
    const int per = gridDim.x >> 3;
    const int tile = (blockIdx.x & 7) * per + (blockIdx.x >> 3);
    const int p0 = tile * 256;

    f32x4 acc[2][4];
#pragma unroll
    for (int i = 0; i < 2; ++i)
#pragma unroll
        for (int j = 0; j < 4; ++j) acc[i][j] = f32x4{0.f, 0.f, 0.f, 0.f};

    for (int cb = 0; cb < 16; ++cb) {
        __syncthreads();
#pragma unroll
        for (int pass = 0; pass < 4; ++pass) {
            int c = pass * 256 + tid;
            int gg = c >> 8, px = c & 255;
            const unsigned short* src = Xt + (size_t)(p0 + px) * CDIM + cb * 32 + gg * 8;
            gload_lds16(src, &s_t[(size_t)c * 8]);
        }
        bf16x8 a[2];
#pragma unroll
        for (int mf = 0; mf < 2; ++mf)
            a[mf] = *(const bf16x8*)(wc + (size_t)((cb * 32 + mf * 16 + ln15) * 32) + g * 8);
        __syncthreads();
        bf16x8 b[4];
#pragma unroll
        for (int nf = 0; nf < 4; ++nf) {
            int slot = g * 256 + wid * 64 + nf * 16 + ln15;
            b[nf] = *(const bf16x8*)&s_t[(size_t)slot * 8];
        }
#pragma unroll
        for (int mf = 0; mf < 2; ++mf)
#pragma unroll
            for (int nf = 0; nf < 4; ++nf)
                acc[mf][nf] = __builtin_amdgcn_mfma_f32_16x16x32_bf16(a[mf], b[nf], acc[mf][nf], 0, 0, 0);
    }
#pragma unroll
    for (int nf = 0; nf < 4; ++nf) {
        const size_t p = (size_t)p0 + wid * 64 + nf * 16 + ln15;
#pragma unroll
        for (int mf = 0; mf < 2; ++mf) {
            const int oc0 = mf * 16 + g * 4;
            const float4 bi = *(const float4*)(cbias + oc0);
            f32x4 v = acc[mf][nf];
            ccv[(size_t)(oc0 + 0) * HW + p] = v[0] + bi.x;
            ccv[(size_t)(oc0 + 1) * HW + p] = v[1] + bi.y;
            ccv[(size_t)(oc0 + 2) * HW + p] = v[2] + bi.z;
            ccv[(size_t)(oc0 + 3) * HW + p] = v[3] + bi.w;
        }
    }
}

// ============================ cov / fc / combine ============================

__global__ __launch_bounds__(256) void cov_accum_k(const float* __restrict__ f,
                                                   const unsigned char* __restrict__ code,
                                                   float* __restrict__ covraw) {
    constexpr int PCH = 256;
    __shared__ float s_f[32][PCH + 1];
    const int i = blockIdx.y;
    const int p0 = blockIdx.x * PCH;
    const int t = threadIdx.x;
    for (int e = t; e < 32 * PCH; e += 256) {
        int row = e >> 8, col = e & (PCH - 1);
        int p = p0 + col;
        float m = ((code[p] >> i) & 1u) ? 1.f : 0.f;
        s_f[row][col] = f[(size_t)row * HW + p] * m;
    }
    __syncthreads();
    const int a = t >> 3;
    const int b0 = (t & 7) * 4;
    float a0 = 0.f, a1 = 0.f, a2 = 0.f, a3 = 0.f;
    for (int p = 0; p < PCH; ++p) {
        float va = s_f[a][p];
        a0 = fmaf(va, s_f[b0 + 0][p], a0);
        a1 = fmaf(va, s_f[b0 + 1][p], a1);
        a2 = fmaf(va, s_f[b0 + 2][p], a2);
        a3 = fmaf(va, s_f[b0 + 3][p], a3);
    }
    float* dst = covraw + i * 1024 + a * 32 + b0;
    atomicAdd(dst + 0, a0);
    atomicAdd(dst + 1, a1);
    atomicAdd(dst + 2, a2);
    atomicAdd(dst + 3, a3);
}

__global__ __launch_bounds__(256) void fc_k(const float* __restrict__ fcw,
                                            const float* __restrict__ fcb,
                                            const float* __restrict__ covraw,
                                            const int* __restrict__ cnt,
                                            float* __restrict__ mats) {
    const int i = blockIdx.y;
    const int wv = threadIdx.x >> 6;
    const int lane = threadIdx.x & 63;
    const int r = blockIdx.x * 4 + wv;
    const float inv = 1.f / fmaxf((float)cnt[i], 1.f);
    float acc = 0.f;
    for (int q = lane; q < 1024; q += 64)
        acc = fmaf(fcw[r * 1024 + q], covraw[i * 1024 + q] * inv, acc);
    for (int off = 32; off; off >>= 1) acc += __shfl_down(acc, off);
    if (lane == 0) mats[i * 1024 + r] = acc + fcb[r];
}

__global__ __launch_bounds__(256) void prep_small_k(const float* __restrict__ sMats,
                                                    const float* __restrict__ cMats,
                                                    const float* __restrict__ unzip_b,
                                                    const float* __restrict__ smean5,
                                                    int n,
                                                    float* __restrict__ tm5,
                                                    float* __restrict__ B5) {
    int t = blockIdx.x * 256 + threadIdx.x;
    if (t < 5 * 1024) {
        int i = t >> 10, rc = t & 1023, r = rc >> 5, c = rc & 31;
        float v;
        if (i < n) {
            float s = 0.f;
            for (int k = 0; k < 32; ++k)
                s = fmaf(sMats[i * 1024 + r * 32 + k], cMats[i * 1024 + k * 32 + c], s);
            v = s;
        } else {
            v = (r == c) ? 1.f : 0.f;
        }
        tm5[t] = v;
    } else if (t < 5 * 1024 + 5 * 512) {
        int u = t - 5 * 1024;
        int i = u >> 9, c = u & 511;
        B5[u] = unzip_b[c] + smean5[i * CDIM + c];
    }
}

__global__ __launch_bounds__(256) void final_k(const float* __restrict__ ccv,
                                               const signed char* __restrict__ fidx,
                                               const float* __restrict__ tm5,
                                               const float* __restrict__ B5,
                                               const float* __restrict__ uw,
                                               float* __restrict__ out) {
    __shared__ float s_tm[5 * 1032];
    __shared__ float s_B[5 * 520];
    const int t = threadIdx.x;
    for (int e = t; e < 5 * 1024; e += 256) {
        int i = e >> 10, rc = e & 1023;
        s_tm[i * 1032 + rc] = tm5[e];
    }
    for (int e = t; e < 5 * 512; e += 256) {
        int i = e >> 9, c = e & 511;
        s_B[i * 520 + c] = B5[e];
    }
    __syncthreads();
    const int p = blockIdx.x * 256 + t;
    const int id = fidx[p];
    float v[32];
#pragma unroll
    for (int k = 0; k < 32; ++k) v[k] = ccv[(size_t)k * HW + p];
    float tv[32];
#pragma unroll
    for (int r = 0; r < 32; ++r) {
        float s = 0.f;
#pragma unroll
        for (int k = 0; k < 32; ++k)
            s = fmaf(s_tm[id * 1032 + r * 32 + k], v[k], s);
        tv[r] = s;
    }
    for (int c = 0; c < CDIM; ++c) {
        float s = s_B[id * 520 + c];
#pragma unroll
        for (int k = 0; k < 32; ++k)
            s = fmaf(uw[c * 32 + k], tv[k], s);
        out[(size_t)c * HW + p] = s;
    }
}

// ============================ launch ============================

extern "C" void kernel_launch(void* const* d_in, const int* in_sizes, int n_in,
                              void* d_out, int out_size, void* d_ws, size_t ws_size,
                              hipStream_t stream) {
    const float* cF = (const float*)d_in[0];
    const float* sF = (const float*)d_in[1];
    const int* cmasks = (const int*)d_in[2];
    const int* smasks = (const int*)d_in[3];
    const float* snet_w1 = (const float*)d_in[4];
    const float* snet_b1 = (const float*)d_in[5];
    const float* snet_w2 = (const float*)d_in[6];
    const float* snet_b2 = (const float*)d_in[7];
    const float* snet_w3 = (const float*)d_in[8];
    const float* snet_b3 = (const float*)d_in[9];
    const float* snet_fcw = (const float*)d_in[10];
    const float* snet_fcb = (const float*)d_in[11];
    const float* cnet_w1 = (const float*)d_in[12];
    const float* cnet_b1 = (const float*)d_in[13];
    const float* cnet_w2 = (const float*)d_in[14];
    const float* cnet_b2 = (const float*)d_in[15];
    const float* cnet_w3 = (const float*)d_in[16];
    const float* cnet_b3 = (const float*)d_in[17];
    const float* cnet_fcw = (const float*)d_in[18];
    const float* cnet_fcb = (const float*)d_in[19];
    const float* compress_w = (const float*)d_in[20];
    const float* compress_b = (const float*)d_in[21];
    const float* unzip_w = (const float*)d_in[22];
    const float* unzip_b = (const float*)d_in[23];
    float* out = (float*)d_out;

    int nmC = in_sizes[2] / HW;
    int nmS = in_sizes[3] / HW;
    int n = nmC < nmS ? nmC : nmS;
    if (n > 4) n = 4;

    char* ws = (char*)d_ws;
    size_t off = 0;
    auto alloc = [&](size_t bytes) {
        size_t o = off;
        off += (bytes + 255) & ~(size_t)255;
        return o;
    };
    char* regA = ws + alloc((size_t)HW * 512 * 2);   // Xt / Y2
    char* regB = ws + alloc((size_t)HW * 256 * 2);   // Y1 / fbuf
    float* ccv  = (float*)(ws + alloc((size_t)32 * HW * 4));
    unsigned short* Wt1s = (unsigned short*)(ws + alloc((size_t)9 * 256 * 512 * 2));
    unsigned short* Wt2s = (unsigned short*)(ws + alloc((size_t)9 * 128 * 256 * 2));
    unsigned short* Wt3s = (unsigned short*)(ws + alloc((size_t)9 * 32 * 128 * 2));
    unsigned short* Wt1c = (unsigned short*)(ws + alloc((size_t)9 * 256 * 512 * 2));
    unsigned short* Wt2c = (unsigned short*)(ws + alloc((size_t)9 * 128 * 256 * 2));
    unsigned short* Wt3c = (unsigned short*)(ws + alloc((size_t)9 * 32 * 128 * 2));
    unsigned short* Wc  = (unsigned short*)(ws + alloc((size_t)32 * 512 * 2));
    unsigned char* ccode = (unsigned char*)(ws + alloc(HW));
    unsigned char* scode = (unsigned char*)(ws + alloc(HW));
    signed char* cidx = (signed char*)(ws + alloc(HW));
    signed char* sidx = (signed char*)(ws + alloc(HW));
    signed char* fidx = (signed char*)(ws + alloc(HW));
    int*   cnt    = (int*)(ws + alloc(8 * 4));
    float* cmean5 = (float*)(ws + alloc(5 * CDIM * 4));
    float* smean5 = (float*)(ws + alloc(5 * CDIM * 4));
    float* covraw = (float*)(ws + alloc(8 * 1024 * 4));
    float* sMats  = (float*)(ws + alloc(4 * 1024 * 4));
    float* cMats  = (float*)(ws + alloc(4 * 1024 * 4));
    float* tm5    = (float*)(ws + alloc(5 * 1024 * 4));
    float* B5     = (float*)(ws + alloc(5 * 512 * 4));
    float* zpf    = (float*)(ws + alloc(256));
    (void)ws_size; (void)n_in; (void)out_size;

    unsigned short* Xt = (unsigned short*)regA;
    unsigned short* Y2 = (unsigned short*)regA;   // overwrites Xt only at conv2 (Xt dead)
    unsigned short* Y1 = (unsigned short*)regB;
    float*          fbuf = (float*)regB;
    const unsigned short* zp = (const unsigned short*)zpf;

    // ---- stage 0: fused prep (zero + all weight transforms) + masks/means/idx ----
    prep_all_k<<<11905, 256, 0, stream>>>(cnt, covraw, zpf, compress_w, Wc,
                                          snet_w1, Wt1s, snet_w2, Wt2s, snet_w3, Wt3s,
                                          cnet_w1, Wt1c, cnet_w2, Wt2c, cnet_w3, Wt3c);
    pack_masks_k<<<HW / 256, 256, 0, stream>>>(cmasks, smasks, n, ccode, scode, cnt);
    masked_means_k<<<2 * CDIM, 256, 0, stream>>>(cF, sF, ccode, scode, cnt, cmean5, smean5);
    idx_maps_k<<<HW / 256, 256, 0, stream>>>(ccode, scode, cnt, n, cidx, sidx, fidx);

    // ---- snet ----
    trans_in_k<<<dim3(HW / 64, 8), 256, 0, stream>>>(sF, smean5, sidx, Xt);
    convmf2_k<512, 256, 128, 128, true ><<<1024, 256, 0, stream>>>(Xt, Wt1s, snet_b1, Y1, zp);
    convmf2_k<256, 128, 128, 128, true ><<<512, 256, 0, stream>>>(Y1, Wt2s, snet_b2, Y2, zp);
    convmf_k<128, 32,  32,  256, 32, 64, false><<<dim3(256, 1), 256, 0, stream>>>(Y2, Wt3s, snet_b3, fbuf, zp);
    cov_accum_k<<<dim3(HW / 256, n), 256, 0, stream>>>(fbuf, scode, covraw);
    fc_k<<<dim3(256, n), 256, 0, stream>>>(snet_fcw, snet_fcb, covraw, cnt + 4, sMats);

    // ---- cnet ----
    trans_in_k<<<dim3(HW / 64, 8), 256, 0, stream>>>(cF, cmean5, cidx, Xt);
    ccv_gemm_k<<<HW / 256, 256, 0, stream>>>(Xt, Wc, compress_b, ccv);   // while Xt alive
    convmf2_k<512, 256, 128, 128, true ><<<1024, 256, 0, stream>>>(Xt, Wt1c, cnet_b1, Y1, zp);
    convmf2_k<256, 128, 128, 128, true ><<<512, 256, 0, stream>>>(Y1, Wt2c, cnet_b2, Y2, zp);
    convmf_k<128, 32,  32,  256, 32, 64, false><<<dim3(256, 1), 256, 0, stream>>>(Y2, Wt3c, cnet_b3, fbuf, zp);
    cov_accum_k<<<dim3(HW / 256, n), 256, 0, stream>>>(fbuf, ccode, covraw + 4 * 1024);
    fc_k<<<dim3(256, n), 256, 0, stream>>>(cnet_fcw, cnet_fcb, covraw + 4 * 1024, cnt, cMats);

    // ---- combine ----
    prep_small_k<<<30, 256, 0, stream>>>(sMats, cMats, unzip_b, smean5, n, tm5, B5);
    final_k<<<HW / 256, 256, 0, stream>>>(ccv, fidx, tm5, B5, unzip_w, out);
}

// Round 12
// 951.213 us; speedup vs baseline: 1.3078x; 1.0119x over previous
//
#include <hip/hip_runtime.h>

#define HDIM 256
#define WDIM 256
#define HW   65536
#define CDIM 512

using bf16x8 = __attribute__((ext_vector_type(8))) short;
using f32x4  = __attribute__((ext_vector_type(4))) float;

__device__ __forceinline__ unsigned short f2bf(float f) {
    unsigned u = __builtin_bit_cast(unsigned, f);
    u += 0x7FFFu + ((u >> 16) & 1u);          // RNE
    return (unsigned short)(u >> 16);
}

__device__ __forceinline__ void gload_lds16(const void* g, void* l) {
    __builtin_amdgcn_global_load_lds((const __attribute__((address_space(1))) unsigned int*)g,
                                     (__attribute__((address_space(3))) unsigned int*)l, 16, 0, 0);
}

// ============================ fused prep (zero + all weight transforms) ============

__device__ __forceinline__ void wtrans_one(const float* __restrict__ w,
                                           unsigned short* __restrict__ wt,
                                           int COUT, int CIN, int t) {
    int oc = t / (CIN * 9);
    int rem = t - oc * (CIN * 9);
    int ci = rem / 9;
    int tap = rem - ci * 9;
    wt[(size_t)(((ci >> 5) * 9 + tap) * COUT + oc) * 32 + (ci & 31)] = f2bf(w[t]);
}

__global__ __launch_bounds__(256) void prep_all_k(int* __restrict__ cnt,
                                                  float* __restrict__ covraw,
                                                  float* __restrict__ zp,
                                                  const float* __restrict__ cw, unsigned short* __restrict__ wc,
                                                  const float* __restrict__ s1, unsigned short* __restrict__ W1s,
                                                  const float* __restrict__ s2, unsigned short* __restrict__ W2s,
                                                  const float* __restrict__ s3, unsigned short* __restrict__ W3s,
                                                  const float* __restrict__ c1, unsigned short* __restrict__ W1c,
                                                  const float* __restrict__ c2, unsigned short* __restrict__ W2c,
                                                  const float* __restrict__ c3, unsigned short* __restrict__ W3c) {
    int t = blockIdx.x * 256 + threadIdx.x;
    if (t < 8264) {
        if (t < 8) cnt[t] = 0;
        else if (t < 8200) covraw[t - 8] = 0.f;
        else if (t < 8264) zp[t - 8200] = 0.f;
        return;
    }
    t -= 8264;
    if (t < 16384) {                       // compress_w -> wc[ci/32][oc][ci%32]
        int oc = t >> 9, ci = t & 511;
        wc[(size_t)((ci >> 5) * 32 + oc) * 32 + (ci & 31)] = f2bf(cw[t]);
        return;
    }
    t -= 16384;
    if (t < 1179648) { wtrans_one(s1, W1s, 256, 512, t); return; }
    t -= 1179648;
    if (t < 294912)  { wtrans_one(s2, W2s, 128, 256, t); return; }
    t -= 294912;
    if (t < 36864)   { wtrans_one(s3, W3s, 32, 128, t); return; }
    t -= 36864;
    if (t < 1179648) { wtrans_one(c1, W1c, 256, 512, t); return; }
    t -= 1179648;
    if (t < 294912)  { wtrans_one(c2, W2c, 128, 256, t); return; }
    t -= 294912;
    if (t < 36864)   { wtrans_one(c3, W3c, 32, 128, t); return; }
}

// ============================ small kernels ============================

__global__ __launch_bounds__(256) void pack_masks_k(const int* __restrict__ cm,
                                                    const int* __restrict__ sm,
                                                    int n,
                                                    unsigned char* __restrict__ ccode,
                                                    unsigned char* __restrict__ scode,
                                                    int* __restrict__ cnt) {
    int p = blockIdx.x * 256 + threadIdx.x;
    unsigned cc = 0, sc = 0;
    for (int i = 0; i < n; ++i) {
        if (cm[i * HW + p] != 0) cc |= (1u << i);
        if (sm[i * HW + p] != 0) sc |= (1u << i);
    }
    ccode[p] = (unsigned char)cc;
    scode[p] = (unsigned char)sc;
    int lane = threadIdx.x & 63;
    for (int i = 0; i < n; ++i) {
        unsigned long long bc = __ballot((cc >> i) & 1);
        unsigned long long bs = __ballot((sc >> i) & 1);
        if (lane == 0) {
            atomicAdd(&cnt[i],     (int)__popcll(bc));
            atomicAdd(&cnt[4 + i], (int)__popcll(bs));
        }
    }
}

// vectorized: float4 pixel loads + packed uint code loads
__global__ __launch_bounds__(256) void masked_means_k(const float* __restrict__ cF,
                                                      const float* __restrict__ sF,
                                                      const unsigned char* __restrict__ ccode,
                                                      const unsigned char* __restrict__ scode,
                                                      const int* __restrict__ cnt,
                                                      float* __restrict__ cmean5,
                                                      float* __restrict__ smean5) {
    int b = blockIdx.x;
    const float* x; const unsigned char* code; const int* cn; float* mout;
    if (b < CDIM) { x = cF; code = ccode; cn = cnt;     mout = cmean5; }
    else          { x = sF; code = scode; cn = cnt + 4; mout = smean5; b -= CDIM; }
    const int c = b;
    const int t = threadIdx.x;
    const float4* x4 = (const float4*)(x + (size_t)c * HW);
    const unsigned* cd4 = (const unsigned*)code;
    float s0 = 0.f, s1 = 0.f, s2 = 0.f, s3 = 0.f;
    for (int i = t; i < HW / 4; i += 256) {
        float4 v = x4[i];
        unsigned cd = cd4[i];
        float vv;
        vv = v.x;
        if (cd & 0x01u) s0 += vv;
        if (cd & 0x02u) s1 += vv;
        if (cd & 0x04u) s2 += vv;
        if (cd & 0x08u) s3 += vv;
        vv = v.y;
        if (cd & 0x0100u) s0 += vv;
        if (cd & 0x0200u) s1 += vv;
        if (cd & 0x0400u) s2 += vv;
        if (cd & 0x0800u) s3 += vv;
        vv = v.z;
        if (cd & 0x010000u) s0 += vv;
        if (cd & 0x020000u) s1 += vv;
        if (cd & 0x040000u) s2 += vv;
        if (cd & 0x080000u) s3 += vv;
        vv = v.w;
        if (cd & 0x01000000u) s0 += vv;
        if (cd & 0x02000000u) s1 += vv;
        if (cd & 0x04000000u) s2 += vv;
        if (cd & 0x08000000u) s3 += vv;
    }
    __shared__ float red[4][256];
    red[0][t] = s0; red[1][t] = s1; red[2][t] = s2; red[3][t] = s3;
    __syncthreads();
    for (int off = 128; off; off >>= 1) {
        if (t < off) {
            red[0][t] += red[0][t + off];
            red[1][t] += red[1][t + off];
            red[2][t] += red[2][t + off];
            red[3][t] += red[3][t + off];
        }
        __syncthreads();
    }
    if (t < 4) mout[t * CDIM + c] = red[t][0] / fmaxf((float)cn[t], 1.f);
    if (t == 4) mout[4 * CDIM + c] = 0.f;
}

__global__ __launch_bounds__(256) void idx_maps_k(const unsigned char* __restrict__ ccode,
                                                  const unsigned char* __restrict__ scode,
                                                  const int* __restrict__ cnt, int n,
                                                  signed char* __restrict__ cidx,
                                                  signed char* __restrict__ sidx,
                                                  signed char* __restrict__ fidx) {
    int p = blockIdx.x * 256 + threadIdx.x;
    int cc = ccode[p], sc = scode[p];
    int ci = 4, si = 4, fi = 4;
    for (int i = 0; i < n; ++i) {
        bool cv = cnt[i] >= 10;
        bool sv = cnt[4 + i] >= 10;
        if (((cc >> i) & 1) && cv) ci = i;
        if (((sc >> i) & 1) && sv) si = i;
        if (((cc >> i) & 1) && cv && sv) fi = i;
    }
    cidx[p] = (signed char)ci;
    sidx[p] = (signed char)si;
    fidx[p] = (signed char)fi;
}

// X[512][HW] f32 -> Xt[HW][512] bf16, fused mean-sub (float4 loads, pair-packed)
__global__ __launch_bounds__(256) void trans_in_k(const float* __restrict__ X,
                                                  const float* __restrict__ mean5,
                                                  const signed char* __restrict__ idx5,
                                                  unsigned short* __restrict__ Xt) {
    __shared__ unsigned s32[64 * 33];     // [px][32 u32 + 1 pad]
    const int tid = threadIdx.x;
    const int p0 = blockIdx.x * 64;
    const int c0 = blockIdx.y * 64;
    const int cpair = tid >> 3;
    const int q = tid & 7;
    const int ch0 = c0 + cpair * 2;
    const float* X0 = X + (size_t)ch0 * HW;
    const float* X1 = X0 + HW;
#pragma unroll
    for (int k = 0; k < 2; ++k) {
        int px0 = (q + k * 8) * 4;
        float4 va = *(const float4*)(X0 + p0 + px0);
        float4 vb = *(const float4*)(X1 + p0 + px0);
        int id4 = *(const int*)(idx5 + p0 + px0);
        float a[4] = {va.x, va.y, va.z, va.w};
        float b[4] = {vb.x, vb.y, vb.z, vb.w};
#pragma unroll
        for (int j = 0; j < 4; ++j) {
            int id = (id4 >> (8 * j)) & 0xFF;
            const float* mr = mean5 + id * CDIM;
            unsigned u = (unsigned)f2bf(a[j] - mr[ch0])
                       | ((unsigned)f2bf(b[j] - mr[ch0 + 1]) << 16);
            s32[(px0 + j) * 33 + cpair] = u;
        }
    }
    __syncthreads();
    const int px = tid >> 2, h = tid & 3;
    const unsigned* rp = &s32[px * 33 + h * 8];
    uint4 u0 = *(const uint4*)(rp);
    uint4 u1 = *(const uint4*)(rp + 4);
    unsigned short* dst = Xt + (size_t)(p0 + px) * CDIM + c0 + h * 16;
    *(uint4*)dst = u0;
    *(uint4*)(dst + 8) = u1;
}

// ============================ MFMA conv v2: 2-phase pipelined, dedup weights ======
// R11 structure + bank-conflict-free LDS layout: chunk order [ky][pxb][g][pxi]
// (16-px blocks; partial block for the 2 halo px). B-frag read at kx=0 is
// addr = base + 16*lane across all 64 lanes (R7's proven zero-conflict pattern).
template <int CIN, int COUT, int BM, int BN, bool RELU>
__global__ __launch_bounds__(256, 2) void convmf2_k(const unsigned short* __restrict__ Xt,
                                                    const unsigned short* __restrict__ Wt,
                                                    const float* __restrict__ bias,
                                                    unsigned short* __restrict__ Yt,
                                                    const unsigned short* __restrict__ zp) {
    constexpr int WM = BM / 4;
    constexpr int FM = WM / 16;
    constexpr int FN = BN / 16;
    constexpr int NCHR = 520;               // per ky row: 8 blocks*64 + 8 partial
    constexpr int NCH = 3 * NCHR;           // 1560 chunks of 16B
    constexpr int NCB = CIN / 32;
    constexpr int TPR = WDIM / BN;          // 2
    constexpr int NBX = HDIM * TPR;         // 512 pixel tiles
    constexpr int PER = NBX / 8;            // 64 pixel tiles per XCD
    __shared__ unsigned short s_tile[2][NCH * 8 + 256];

    const int tid = threadIdx.x;
    const int ln = tid & 63, wid = tid >> 6;
    const int ln15 = ln & 15, g = ln >> 4;

    // XCD-aware decode (bijective: blocks b = xcd + 8*k, k in [0, PER*GRIDY))
    const int b = blockIdx.x;
    const int xcd = b & 7;
    const int k = b >> 3;
    const int xt = xcd * PER + (k % PER);   // pixel tile [0, NBX)
    const int yt = k / PER;                 // ocb index [0, GRIDY)

    const int y0 = xt / TPR;
    const int x0 = (xt % TPR) * BN;
    const int ocb = yt * BM;

    auto stage = [&](int buf, int cb) {
#pragma unroll
        for (int c0 = 0; c0 < NCH; c0 += 256) {
            int c = c0 + tid;
            if (c < NCH) {
                int ky = c / NCHR;
                int rem = c - ky * NCHR;
                int px, gg;
                if (rem < 512) {
                    int pxb = rem >> 6;
                    int q = rem & 63;
                    gg = q >> 4;
                    px = pxb * 16 + (q & 15);
                } else {
                    int e = rem - 512;
                    gg = e >> 1;
                    px = 128 + (e & 1);
                }
                int y = y0 + ky - 1;
                int x = x0 - 1 + px;
                bool ok = ((unsigned)y < HDIM) && ((unsigned)x < WDIM);
                const unsigned short* src = ok
                    ? Xt + (size_t)(y * WDIM + x) * CIN + cb * 32 + gg * 8
                    : zp;
                gload_lds16(src, &s_tile[buf][(size_t)c * 8]);
            }
        }
    };

    f32x4 acc[FM][FN];
#pragma unroll
    for (int i = 0; i < FM; ++i)
#pragma unroll
        for (int j = 0; j < FN; ++j) acc[i][j] = f32x4{0.f, 0.f, 0.f, 0.f};

    const unsigned short* wfb = Wt + (size_t)(ocb + wid * WM + ln15) * 32 + g * 8;

    stage(0, 0);

    for (int cb = 0; cb < NCB; ++cb) {
        const int buf = cb & 1;
        __syncthreads();
        bf16x8 wreg[9][FM];
#pragma unroll
        for (int tap = 0; tap < 9; ++tap)
#pragma unroll
            for (int mf = 0; mf < FM; ++mf)
                wreg[tap][mf] = *(const bf16x8*)(wfb + (size_t)((cb * 9 + tap) * COUT + mf * 16) * 32);
        if (cb + 1 < NCB) stage(buf ^ 1, cb + 1);
        const unsigned short* st = &s_tile[buf][0];
#pragma unroll
        for (int tap = 0; tap < 9; ++tap) {
            const int ky = tap / 3, kx = tap - ky * 3;
            bf16x8 bfr[FN];
#pragma unroll
            for (int nf = 0; nf < FN; ++nf) {
                int px = kx + nf * 16 + ln15;
                int chunk = (px < 128)
                    ? ky * NCHR + ((px >> 4) << 6) + (g << 4) + (px & 15)
                    : ky * NCHR + 512 + (g << 1) + (px - 128);
                bfr[nf] = *(const bf16x8*)&st[(size_t)chunk * 8];
            }
#pragma unroll
            for (int mf = 0; mf < FM; ++mf)
#pragma unroll
                for (int nf = 0; nf < FN; ++nf)
                    acc[mf][nf] = __builtin_amdgcn_mfma_f32_16x16x32_bf16(wreg[tap][mf], bfr[nf], acc[mf][nf], 0, 0, 0);
        }
    }

    const int p0 = y0 * WDIM + x0;
#pragma unroll
    for (int nf = 0; nf < FN; ++nf) {
        const size_t p = (size_t)p0 + nf * 16 + ln15;
#pragma unroll
        for (int mf = 0; mf < FM; ++mf) {
            const int oc0 = ocb + wid * WM + mf * 16 + g * 4;
            const float4 bi = *(const float4*)(bias + oc0);
            f32x4 v = acc[mf][nf];
            float r0 = v[0] + bi.x, r1 = v[1] + bi.y, r2 = v[2] + bi.z, r3 = v[3] + bi.w;
            if (RELU) {
                r0 = fmaxf(r0, 0.f); r1 = fmaxf(r1, 0.f);
                r2 = fmaxf(r2, 0.f); r3 = fmaxf(r3, 0.f);
            }
            unsigned lo = (unsigned)f2bf(r0) | ((unsigned)f2bf(r1) << 16);
            unsigned hi = (unsigned)f2bf(r2) | ((unsigned)f2bf(r3) << 16);
            *(uint2*)(Yt + p * COUT + oc0) = uint2{lo, hi};
        }
    }
}

// ============================ MFMA conv v1 (conv3, f32 out) ============================
template <int CIN, int COUT, int BM, int BN, int WM, int WN, bool RELU>
__global__ __launch_bounds__(256, 2) void convmf_k(const unsigned short* __restrict__ Xt,
                                                   const unsigned short* __restrict__ Wt,
                                                   const float* __restrict__ bias,
                                                   float* __restrict__ Yf,
                                                   const unsigned short* __restrict__ zp) {
    constexpr int WAVES_N = BN / WN;
    constexpr int FM = WM / 16, FN = WN / 16;
    constexpr int PXT = BN + 2;
    constexpr int PXTP = BN + 6;
    constexpr int NCH = 12 * PXTP;
    constexpr int NCHP = (NCH + 255) & ~255;
    __shared__ unsigned short s_tile[NCHP * 8];

    const int tid = threadIdx.x;
    const int ln = tid & 63, wid = tid >> 6;
    const int ln15 = ln & 15, g = ln >> 4;
    const int wm_i = wid / WAVES_N, wn_i = wid % WAVES_N;

    // XCD swizzle (grid.x divisible by 8)
    const int per = gridDim.x >> 3;
    const int tile = (blockIdx.x & 7) * per + (blockIdx.x >> 3);

    constexpr int TPR = WDIM / BN;
    const int y0 = tile / TPR;
    const int x0 = (tile % TPR) * BN;
    const int ocb = blockIdx.y * BM;

    f32x4 acc[FM][FN];
#pragma unroll
    for (int i = 0; i < FM; ++i)
#pragma unroll
        for (int j = 0; j < FN; ++j) acc[i][j] = f32x4{0.f, 0.f, 0.f, 0.f};

    const unsigned short* wfb = Wt + (size_t)(ocb + wm_i * WM + ln15) * 32 + g * 8;

    for (int cb = 0; cb < CIN / 32; ++cb) {
        __syncthreads();
        for (int c0 = 0; c0 < NCH; c0 += 256) {
            int c = c0 + tid;
            if (c < NCH) {
                int grow = c / PXTP;
                int px = c - grow * PXTP;
                int ky = grow >> 2, gg = grow & 3;
                int y = y0 + ky - 1;
                int x = x0 - 1 + px;
                bool ok = (px < PXT) && ((unsigned)y < HDIM) && ((unsigned)x < WDIM);
                const unsigned short* src = ok
                    ? Xt + (size_t)(y * WDIM + x) * CIN + cb * 32 + gg * 8
                    : zp;
                gload_lds16(src, &s_tile[(size_t)(c0 + wid * 64) * 8]);
            }
        }
        bf16x8 wreg[9][FM];
#pragma unroll
        for (int tap = 0; tap < 9; ++tap)
#pragma unroll
            for (int mf = 0; mf < FM; ++mf)
                wreg[tap][mf] = *(const bf16x8*)(wfb + (size_t)((cb * 9 + tap) * COUT + mf * 16) * 32);
        __syncthreads();
#pragma unroll
        for (int tap = 0; tap < 9; ++tap) {
            const int ky = tap / 3, kx = tap - ky * 3;
            bf16x8 b[FN];
#pragma unroll
            for (int nf = 0; nf < FN; ++nf) {
                int slot = (ky * 4 + g) * PXTP + kx + wn_i * WN + nf * 16 + ln15;
                b[nf] = *(const bf16x8*)&s_tile[(size_t)slot * 8];
            }
#pragma unroll
            for (int mf = 0; mf < FM; ++mf)
#pragma unroll
                for (int nf = 0; nf < FN; ++nf)
                    acc[mf][nf] = __builtin_amdgcn_mfma_f32_16x16x32_bf16(wreg[tap][mf], b[nf], acc[mf][nf], 0, 0, 0);
        }
    }

    const int p0 = y0 * WDIM + x0;
#pragma unroll
    for (int nf = 0; nf < FN; ++nf) {
        const size_t p = (size_t)p0 + wn_i * WN + nf * 16 + ln15;
#pragma unroll
        for (int mf = 0; mf < FM; ++mf) {
            const int oc0 = ocb + wm_i * WM + mf * 16 + g * 4;
            const float4 bi = *(const float4*)(bias + oc0);
            f32x4 v = acc[mf][nf];
            float r0 = v[0] + bi.x, r1 = v[1] + bi.y, r2 = v[2] + bi.z, r3 = v[3] + bi.w;
            if (RELU) {
                r0 = fmaxf(r0, 0.f); r1 = fmaxf(r1, 0.f);
                r2 = fmaxf(r2, 0.f); r3 = fmaxf(r3, 0.f);
            }
            Yf[(size_t)(oc0 + 0) * HW + p] = r0;
            Yf[(size_t)(oc0 + 1) * HW + p] = r1;
            Yf[(size_t)(oc0 + 2) * HW + p] = r2;
            Yf[(size_t)(oc0 + 3) * HW + p] = r3;
        }
    }
}

// ============================ compress as MFMA GEMM from Xt ============================
__global__ __launch_bounds__(256, 2) void ccv_gemm_k(const unsigned short* __restrict__ Xt,
                                                     const unsigned short* __restrict__ wc,
                                                     const float* __restrict__ cbias,
                                                     float* __restrict__ ccv) {
    __shared__ unsigned short s_t[1024 * 8];
    const int tid = threadIdx.x;
    const int ln = tid & 63, wid = tid >> 6;
    const int ln15 = ln & 15, g = ln >> 4;
    const int per = gridDim.x >> 3;
    const int tile = (blockIdx.x & 7) * per + (blockIdx.x >> 3);
    const int p0 = tile * 256;

    f32x4 acc[2][4];
#pragma unroll
    for (int i = 0; i < 2; ++i)
#pragma unroll
        for (int j = 0; j < 4; ++j) acc[i][j] = f32x4{0.f, 0.f, 0.f, 0.f};

    for (int cb = 0; cb < 16; ++cb) {
        __syncthreads();
#pragma unroll
        for (int pass = 0; pass < 4; ++pass) {
            int c = pass * 256 + tid;
            int gg = c >> 8, px = c & 255;
            const unsigned short* src = Xt + (size_t)(p0 + px) * CDIM + cb * 32 + gg * 8;
            gload_lds16(src, &s_t[(size_t)c * 8]);
        }
        bf16x8 a[2];
#pragma unroll
        for (int mf = 0; mf < 2; ++mf)
            a[mf] = *(const bf16x8*)(wc + (size_t)((cb * 32 + mf * 16 + ln15) * 32) + g * 8);
        __syncthreads();
        bf16x8 b[4];
#pragma unroll
        for (int nf = 0; nf < 4; ++nf) {
            int slot = g * 256 + wid * 64 + nf * 16 + ln15;
            b[nf] = *(const bf16x8*)&s_t[(size_t)slot * 8];
        }
#pragma unroll
        for (int mf = 0; mf < 2; ++mf)
#pragma unroll
            for (int nf = 0; nf < 4; ++nf)
                acc[mf][nf] = __builtin_amdgcn_mfma_f32_16x16x32_bf16(a[mf], b[nf], acc[mf][nf], 0, 0, 0);
    }
#pragma unroll
    for (int nf = 0; nf < 4; ++nf) {
        const size_t p = (size_t)p0 + wid * 64 + nf * 16 + ln15;
#pragma unroll
        for (int mf = 0; mf < 2; ++mf) {
            const int oc0 = mf * 16 + g * 4;
            const float4 bi = *(const float4*)(cbias + oc0);
            f32x4 v = acc[mf][nf];
            ccv[(size_t)(oc0 + 0) * HW + p] = v[0] + bi.x;
            ccv[(size_t)(oc0 + 1) * HW + p] = v[1] + bi.y;
            ccv[(size_t)(oc0 + 2) * HW + p] = v[2] + bi.z;
            ccv[(size_t)(oc0 + 3) * HW + p] = v[3] + bi.w;
        }
    }
}

// ============================ cov / fc / combine ============================

__global__ __launch_bounds__(256) void cov_accum_k(const float* __restrict__ f,
                                                   const unsigned char* __restrict__ code,
                                                   float* __restrict__ covraw) {
    constexpr int PCH = 256;
    __shared__ float s_f[32][PCH + 1];
    const int i = blockIdx.y;
    const int p0 = blockIdx.x * PCH;
    const int t = threadIdx.x;
    for (int e = t; e < 32 * PCH; e += 256) {
        int row = e >> 8, col = e & (PCH - 1);
        int p = p0 + col;
        float m = ((code[p] >> i) & 1u) ? 1.f : 0.f;
        s_f[row][col] = f[(size_t)row * HW + p] * m;
    }
    __syncthreads();
    const int a = t >> 3;
    const int b0 = (t & 7) * 4;
    float a0 = 0.f, a1 = 0.f, a2 = 0.f, a3 = 0.f;
    for (int p = 0; p < PCH; ++p) {
        float va = s_f[a][p];
        a0 = fmaf(va, s_f[b0 + 0][p], a0);
        a1 = fmaf(va, s_f[b0 + 1][p], a1);
        a2 = fmaf(va, s_f[b0 + 2][p], a2);
        a3 = fmaf(va, s_f[b0 + 3][p], a3);
    }
    float* dst = covraw + i * 1024 + a * 32 + b0;
    atomicAdd(dst + 0, a0);
    atomicAdd(dst + 1, a1);
    atomicAdd(dst + 2, a2);
    atomicAdd(dst + 3, a3);
}

__global__ __launch_bounds__(256) void fc_k(const float* __restrict__ fcw,
                                            const float* __restrict__ fcb,
                                            const float* __restrict__ covraw,
                                            const int* __restrict__ cnt,
                                            float* __restrict__ mats) {
    const int i = blockIdx.y;
    const int wv = threadIdx.x >> 6;
    const int lane = threadIdx.x & 63;
    const int r = blockIdx.x * 4 + wv;
    const float inv = 1.f / fmaxf((float)cnt[i], 1.f);
    float acc = 0.f;
    for (int q = lane; q < 1024; q += 64)
        acc = fmaf(fcw[r * 1024 + q], covraw[i * 1024 + q] * inv, acc);
    for (int off = 32; off; off >>= 1) acc += __shfl_down(acc, off);
    if (lane == 0) mats[i * 1024 + r] = acc + fcb[r];
}

__global__ __launch_bounds__(256) void prep_small_k(const float* __restrict__ sMats,
                                                    const float* __restrict__ cMats,
                                                    const float* __restrict__ unzip_b,
                                                    const float* __restrict__ smean5,
                                                    int n,
                                                    float* __restrict__ tm5,
                                                    float* __restrict__ B5) {
    int t = blockIdx.x * 256 + threadIdx.x;
    if (t < 5 * 1024) {
        int i = t >> 10, rc = t & 1023, r = rc >> 5, c = rc & 31;
        float v;
        if (i < n) {
            float s = 0.f;
            for (int k = 0; k < 32; ++k)
                s = fmaf(sMats[i * 1024 + r * 32 + k], cMats[i * 1024 + k * 32 + c], s);
            v = s;
        } else {
            v = (r == c) ? 1.f : 0.f;
        }
        tm5[t] = v;
    } else if (t < 5 * 1024 + 5 * 512) {
        int u = t - 5 * 1024;
        int i = u >> 9, c = u & 511;
        B5[u] = unzip_b[c] + smean5[i * CDIM + c];
    }
}

__global__ __launch_bounds__(256) void final_k(const float* __restrict__ ccv,
                                               const signed char* __restrict__ fidx,
                                               const float* __restrict__ tm5,
                                               const float* __restrict__ B5,
                                               const float* __restrict__ uw,
                                               float* __restrict__ out) {
    __shared__ float s_tm[5 * 1032];
    __shared__ float s_B[5 * 520];
    const int t = threadIdx.x;
    for (int e = t; e < 5 * 1024; e += 256) {
        int i = e >> 10, rc = e & 1023;
        s_tm[i * 1032 + rc] = tm5[e];
    }
    for (int e = t; e < 5 * 512; e += 256) {
        int i = e >> 9, c = e & 511;
        s_B[i * 520 + c] = B5[e];
    }
    __syncthreads();
    const int p = blockIdx.x * 256 + t;
    const int id = fidx[p];
    float v[32];
#pragma unroll
    for (int k = 0; k < 32; ++k) v[k] = ccv[(size_t)k * HW + p];
    float tv[32];
#pragma unroll
    for (int r = 0; r < 32; ++r) {
        float s = 0.f;
#pragma unroll
        for (int k = 0; k < 32; ++k)
            s = fmaf(s_tm[id * 1032 + r * 32 + k], v[k], s);
        tv[r] = s;
    }
    for (int c = 0; c < CDIM; ++c) {
        float s = s_B[id * 520 + c];
#pragma unroll
        for (int k = 0; k < 32; ++k)
            s = fmaf(uw[c * 32 + k], tv[k], s);
        out[(size_t)c * HW + p] = s;
    }
}

// ============================ launch ============================

extern "C" void kernel_launch(void* const* d_in, const int* in_sizes, int n_in,
                              void* d_out, int out_size, void* d_ws, size_t ws_size,
                              hipStream_t stream) {
    const float* cF = (const float*)d_in[0];
    const float* sF = (const float*)d_in[1];
    const int* cmasks = (const int*)d_in[2];
    const int* smasks = (const int*)d_in[3];
    const float* snet_w1 = (const float*)d_in[4];
    const float* snet_b1 = (const float*)d_in[5];
    const float* snet_w2 = (const float*)d_in[6];
    const float* snet_b2 = (const float*)d_in[7];
    const float* snet_w3 = (const float*)d_in[8];
    const float* snet_b3 = (const float*)d_in[9];
    const float* snet_fcw = (const float*)d_in[10];
    const float* snet_fcb = (const float*)d_in[11];
    const float* cnet_w1 = (const float*)d_in[12];
    const float* cnet_b1 = (const float*)d_in[13];
    const float* cnet_w2 = (const float*)d_in[14];
    const float* cnet_b2 = (const float*)d_in[15];
    const float* cnet_w3 = (const float*)d_in[16];
    const float* cnet_b3 = (const float*)d_in[17];
    const float* cnet_fcw = (const float*)d_in[18];
    const float* cnet_fcb = (const float*)d_in[19];
    const float* compress_w = (const float*)d_in[20];
    const float* compress_b = (const float*)d_in[21];
    const float* unzip_w = (const float*)d_in[22];
    const float* unzip_b = (const float*)d_in[23];
    float* out = (float*)d_out;

    int nmC = in_sizes[2] / HW;
    int nmS = in_sizes[3] / HW;
    int n = nmC < nmS ? nmC : nmS;
    if (n > 4) n = 4;

    char* ws = (char*)d_ws;
    size_t off = 0;
    auto alloc = [&](size_t bytes) {
        size_t o = off;
        off += (bytes + 255) & ~(size_t)255;
        return o;
    };
    char* regA = ws + alloc((size_t)HW * 512 * 2);   // Xt / Y2
    char* regB = ws + alloc((size_t)HW * 256 * 2);   // Y1 / fbuf
    float* ccv  = (float*)(ws + alloc((size_t)32 * HW * 4));
    unsigned short* Wt1s = (unsigned short*)(ws + alloc((size_t)9 * 256 * 512 * 2));
    unsigned short* Wt2s = (unsigned short*)(ws + alloc((size_t)9 * 128 * 256 * 2));
    unsigned short* Wt3s = (unsigned short*)(ws + alloc((size_t)9 * 32 * 128 * 2));
    unsigned short* Wt1c = (unsigned short*)(ws + alloc((size_t)9 * 256 * 512 * 2));
    unsigned short* Wt2c = (unsigned short*)(ws + alloc((size_t)9 * 128 * 256 * 2));
    unsigned short* Wt3c = (unsigned short*)(ws + alloc((size_t)9 * 32 * 128 * 2));
    unsigned short* Wc  = (unsigned short*)(ws + alloc((size_t)32 * 512 * 2));
    unsigned char* ccode = (unsigned char*)(ws + alloc(HW));
    unsigned char* scode = (unsigned char*)(ws + alloc(HW));
    signed char* cidx = (signed char*)(ws + alloc(HW));
    signed char* sidx = (signed char*)(ws + alloc(HW));
    signed char* fidx = (signed char*)(ws + alloc(HW));
    int*   cnt    = (int*)(ws + alloc(8 * 4));
    float* cmean5 = (float*)(ws + alloc(5 * CDIM * 4));
    float* smean5 = (float*)(ws + alloc(5 * CDIM * 4));
    float* covraw = (float*)(ws + alloc(8 * 1024 * 4));
    float* sMats  = (float*)(ws + alloc(4 * 1024 * 4));
    float* cMats  = (float*)(ws + alloc(4 * 1024 * 4));
    float* tm5    = (float*)(ws + alloc(5 * 1024 * 4));
    float* B5     = (float*)(ws + alloc(5 * 512 * 4));
    float* zpf    = (float*)(ws + alloc(256));
    (void)ws_size; (void)n_in; (void)out_size;

    unsigned short* Xt = (unsigned short*)regA;
    unsigned short* Y2 = (unsigned short*)regA;   // overwrites Xt only at conv2 (Xt dead)
    unsigned short* Y1 = (unsigned short*)regB;
    float*          fbuf = (float*)regB;
    const unsigned short* zp = (const unsigned short*)zpf;

    // ---- stage 0: fused prep (zero + all weight transforms) + masks/means/idx ----
    prep_all_k<<<11905, 256, 0, stream>>>(cnt, covraw, zpf, compress_w, Wc,
                                          snet_w1, Wt1s, snet_w2, Wt2s, snet_w3, Wt3s,
                                          cnet_w1, Wt1c, cnet_w2, Wt2c, cnet_w3, Wt3c);
    pack_masks_k<<<HW / 256, 256, 0, stream>>>(cmasks, smasks, n, ccode, scode, cnt);
    masked_means_k<<<2 * CDIM, 256, 0, stream>>>(cF, sF, ccode, scode, cnt, cmean5, smean5);
    idx_maps_k<<<HW / 256, 256, 0, stream>>>(ccode, scode, cnt, n, cidx, sidx, fidx);

    // ---- snet ----
    trans_in_k<<<dim3(HW / 64, 8), 256, 0, stream>>>(sF, smean5, sidx, Xt);
    convmf2_k<512, 256, 128, 128, true ><<<1024, 256, 0, stream>>>(Xt, Wt1s, snet_b1, Y1, zp);
    convmf2_k<256, 128, 128, 128, true ><<<512, 256, 0, stream>>>(Y1, Wt2s, snet_b2, Y2, zp);
    convmf_k<128, 32,  32,  256, 32, 64, false><<<dim3(256, 1), 256, 0, stream>>>(Y2, Wt3s, snet_b3, fbuf, zp);
    cov_accum_k<<<dim3(HW / 256, n), 256, 0, stream>>>(fbuf, scode, covraw);
    fc_k<<<dim3(256, n), 256, 0, stream>>>(snet_fcw, snet_fcb, covraw, cnt + 4, sMats);

    // ---- cnet ----
    trans_in_k<<<dim3(HW / 64, 8), 256, 0, stream>>>(cF, cmean5, cidx, Xt);
    ccv_gemm_k<<<HW / 256, 256, 0, stream>>>(Xt, Wc, compress_b, ccv);   // while Xt alive
    convmf2_k<512, 256, 128, 128, true ><<<1024, 256, 0, stream>>>(Xt, Wt1c, cnet_b1, Y1, zp);
    convmf2_k<256, 128, 128, 128, true ><<<512, 256, 0, stream>>>(Y1, Wt2c, cnet_b2, Y2, zp);
    convmf_k<128, 32,  32,  256, 32, 64, false><<<dim3(256, 1), 256, 0, stream>>>(Y2, Wt3c, cnet_b3, fbuf, zp);
    cov_accum_k<<<dim3(HW / 256, n), 256, 0, stream>>>(fbuf, ccode, covraw + 4 * 1024);
    fc_k<<<dim3(256, n), 256, 0, stream>>>(cnet_fcw, cnet_fcb, covraw + 4 * 1024, cnt, cMats);

    // ---- combine ----
    prep_small_k<<<30, 256, 0, stream>>>(sMats, cMats, unzip_b, smean5, n, tm5, B5);
    final_k<<<HW / 256, 256, 0, stream>>>(ccv, fidx, tm5, B5, unzip_w, out);
}

// Round 13
// 882.313 us; speedup vs baseline: 1.4100x; 1.0781x over previous
//
#include <hip/hip_runtime.h>

#define HDIM 256
#define WDIM 256
#define HW   65536
#define CDIM 512

using bf16x8 = __attribute__((ext_vector_type(8))) short;
using f32x4  = __attribute__((ext_vector_type(4))) float;

__device__ __forceinline__ unsigned short f2bf(float f) {
    unsigned u = __builtin_bit_cast(unsigned, f);
    u += 0x7FFFu + ((u >> 16) & 1u);          // RNE
    return (unsigned short)(u >> 16);
}

__device__ __forceinline__ void gload_lds16(const void* g, void* l) {
    __builtin_amdgcn_global_load_lds((const __attribute__((address_space(1))) unsigned int*)g,
                                     (__attribute__((address_space(3))) unsigned int*)l, 16, 0, 0);
}

// ============================ fused prep (zero + all weight transforms) ============

__device__ __forceinline__ void wtrans_one(const float* __restrict__ w,
                                           unsigned short* __restrict__ wt,
                                           int COUT, int CIN, int t) {
    int oc = t / (CIN * 9);
    int rem = t - oc * (CIN * 9);
    int ci = rem / 9;
    int tap = rem - ci * 9;
    wt[(size_t)(((ci >> 5) * 9 + tap) * COUT + oc) * 32 + (ci & 31)] = f2bf(w[t]);
}

__global__ __launch_bounds__(256) void prep_all_k(int* __restrict__ cnt,
                                                  float* __restrict__ covraw,
                                                  float* __restrict__ zp,
                                                  const float* __restrict__ cw, unsigned short* __restrict__ wc,
                                                  const float* __restrict__ s1, unsigned short* __restrict__ W1s,
                                                  const float* __restrict__ s2, unsigned short* __restrict__ W2s,
                                                  const float* __restrict__ s3, unsigned short* __restrict__ W3s,
                                                  const float* __restrict__ c1, unsigned short* __restrict__ W1c,
                                                  const float* __restrict__ c2, unsigned short* __restrict__ W2c,
                                                  const float* __restrict__ c3, unsigned short* __restrict__ W3c) {
    int t = blockIdx.x * 256 + threadIdx.x;
    if (t < 8264) {
        if (t < 8) cnt[t] = 0;
        else if (t < 8200) covraw[t - 8] = 0.f;
        else if (t < 8264) zp[t - 8200] = 0.f;
        return;
    }
    t -= 8264;
    if (t < 16384) {                       // compress_w -> wc[ci/32][oc][ci%32]
        int oc = t >> 9, ci = t & 511;
        wc[(size_t)((ci >> 5) * 32 + oc) * 32 + (ci & 31)] = f2bf(cw[t]);
        return;
    }
    t -= 16384;
    if (t < 1179648) { wtrans_one(s1, W1s, 256, 512, t); return; }
    t -= 1179648;
    if (t < 294912)  { wtrans_one(s2, W2s, 128, 256, t); return; }
    t -= 294912;
    if (t < 36864)   { wtrans_one(s3, W3s, 32, 128, t); return; }
    t -= 36864;
    if (t < 1179648) { wtrans_one(c1, W1c, 256, 512, t); return; }
    t -= 1179648;
    if (t < 294912)  { wtrans_one(c2, W2c, 128, 256, t); return; }
    t -= 294912;
    if (t < 36864)   { wtrans_one(c3, W3c, 32, 128, t); return; }
}

// ============================ small kernels ============================

__global__ __launch_bounds__(256) void pack_masks_k(const int* __restrict__ cm,
                                                    const int* __restrict__ sm,
                                                    int n,
                                                    unsigned char* __restrict__ ccode,
                                                    unsigned char* __restrict__ scode,
                                                    int* __restrict__ cnt) {
    int p = blockIdx.x * 256 + threadIdx.x;
    unsigned cc = 0, sc = 0;
    for (int i = 0; i < n; ++i) {
        if (cm[i * HW + p] != 0) cc |= (1u << i);
        if (sm[i * HW + p] != 0) sc |= (1u << i);
    }
    ccode[p] = (unsigned char)cc;
    scode[p] = (unsigned char)sc;
    int lane = threadIdx.x & 63;
    for (int i = 0; i < n; ++i) {
        unsigned long long bc = __ballot((cc >> i) & 1);
        unsigned long long bs = __ballot((sc >> i) & 1);
        if (lane == 0) {
            atomicAdd(&cnt[i],     (int)__popcll(bc));
            atomicAdd(&cnt[4 + i], (int)__popcll(bs));
        }
    }
}

// vectorized: float4 pixel loads + packed uint code loads
__global__ __launch_bounds__(256) void masked_means_k(const float* __restrict__ cF,
                                                      const float* __restrict__ sF,
                                                      const unsigned char* __restrict__ ccode,
                                                      const unsigned char* __restrict__ scode,
                                                      const int* __restrict__ cnt,
                                                      float* __restrict__ cmean5,
                                                      float* __restrict__ smean5) {
    int b = blockIdx.x;
    const float* x; const unsigned char* code; const int* cn; float* mout;
    if (b < CDIM) { x = cF; code = ccode; cn = cnt;     mout = cmean5; }
    else          { x = sF; code = scode; cn = cnt + 4; mout = smean5; b -= CDIM; }
    const int c = b;
    const int t = threadIdx.x;
    const float4* x4 = (const float4*)(x + (size_t)c * HW);
    const unsigned* cd4 = (const unsigned*)code;
    float s0 = 0.f, s1 = 0.f, s2 = 0.f, s3 = 0.f;
    for (int i = t; i < HW / 4; i += 256) {
        float4 v = x4[i];
        unsigned cd = cd4[i];
        float vv;
        vv = v.x;
        if (cd & 0x01u) s0 += vv;
        if (cd & 0x02u) s1 += vv;
        if (cd & 0x04u) s2 += vv;
        if (cd & 0x08u) s3 += vv;
        vv = v.y;
        if (cd & 0x0100u) s0 += vv;
        if (cd & 0x0200u) s1 += vv;
        if (cd & 0x0400u) s2 += vv;
        if (cd & 0x0800u) s3 += vv;
        vv = v.z;
        if (cd & 0x010000u) s0 += vv;
        if (cd & 0x020000u) s1 += vv;
        if (cd & 0x040000u) s2 += vv;
        if (cd & 0x080000u) s3 += vv;
        vv = v.w;
        if (cd & 0x01000000u) s0 += vv;
        if (cd & 0x02000000u) s1 += vv;
        if (cd & 0x04000000u) s2 += vv;
        if (cd & 0x08000000u) s3 += vv;
    }
    __shared__ float red[4][256];
    red[0][t] = s0; red[1][t] = s1; red[2][t] = s2; red[3][t] = s3;
    __syncthreads();
    for (int off = 128; off; off >>= 1) {
        if (t < off) {
            red[0][t] += red[0][t + off];
            red[1][t] += red[1][t + off];
            red[2][t] += red[2][t + off];
            red[3][t] += red[3][t + off];
        }
        __syncthreads();
    }
    if (t < 4) mout[t * CDIM + c] = red[t][0] / fmaxf((float)cn[t], 1.f);
    if (t == 4) mout[4 * CDIM + c] = 0.f;
}

__global__ __launch_bounds__(256) void idx_maps_k(const unsigned char* __restrict__ ccode,
                                                  const unsigned char* __restrict__ scode,
                                                  const int* __restrict__ cnt, int n,
                                                  signed char* __restrict__ cidx,
                                                  signed char* __restrict__ sidx,
                                                  signed char* __restrict__ fidx) {
    int p = blockIdx.x * 256 + threadIdx.x;
    int cc = ccode[p], sc = scode[p];
    int ci = 4, si = 4, fi = 4;
    for (int i = 0; i < n; ++i) {
        bool cv = cnt[i] >= 10;
        bool sv = cnt[4 + i] >= 10;
        if (((cc >> i) & 1) && cv) ci = i;
        if (((sc >> i) & 1) && sv) si = i;
        if (((cc >> i) & 1) && cv && sv) fi = i;
    }
    cidx[p] = (signed char)ci;
    sidx[p] = (signed char)si;
    fidx[p] = (signed char)fi;
}

// X[512][HW] f32 -> Xt[HW][512] bf16, fused mean-sub (float4 loads, pair-packed)
__global__ __launch_bounds__(256) void trans_in_k(const float* __restrict__ X,
                                                  const float* __restrict__ mean5,
                                                  const signed char* __restrict__ idx5,
                                                  unsigned short* __restrict__ Xt) {
    __shared__ unsigned s32[64 * 33];     // [px][32 u32 + 1 pad]
    const int tid = threadIdx.x;
    const int p0 = blockIdx.x * 64;
    const int c0 = blockIdx.y * 64;
    const int cpair = tid >> 3;
    const int q = tid & 7;
    const int ch0 = c0 + cpair * 2;
    const float* X0 = X + (size_t)ch0 * HW;
    const float* X1 = X0 + HW;
#pragma unroll
    for (int k = 0; k < 2; ++k) {
        int px0 = (q + k * 8) * 4;
        float4 va = *(const float4*)(X0 + p0 + px0);
        float4 vb = *(const float4*)(X1 + p0 + px0);
        int id4 = *(const int*)(idx5 + p0 + px0);
        float a[4] = {va.x, va.y, va.z, va.w};
        float b[4] = {vb.x, vb.y, vb.z, vb.w};
#pragma unroll
        for (int j = 0; j < 4; ++j) {
            int id = (id4 >> (8 * j)) & 0xFF;
            const float* mr = mean5 + id * CDIM;
            unsigned u = (unsigned)f2bf(a[j] - mr[ch0])
                       | ((unsigned)f2bf(b[j] - mr[ch0 + 1]) << 16);
            s32[(px0 + j) * 33 + cpair] = u;
        }
    }
    __syncthreads();
    const int px = tid >> 2, h = tid & 3;
    const unsigned* rp = &s32[px * 33 + h * 8];
    uint4 u0 = *(const uint4*)(rp);
    uint4 u1 = *(const uint4*)(rp + 4);
    unsigned short* dst = Xt + (size_t)(p0 + px) * CDIM + c0 + h * 16;
    *(uint4*)dst = u0;
    *(uint4*)(dst + 8) = u1;
}

// ============================ MFMA conv v2 (R12: conflict-free LDS layout) ======
template <int CIN, int COUT, int BM, int BN, bool RELU>
__global__ __launch_bounds__(256, 2) void convmf2_k(const unsigned short* __restrict__ Xt,
                                                    const unsigned short* __restrict__ Wt,
                                                    const float* __restrict__ bias,
                                                    unsigned short* __restrict__ Yt,
                                                    const unsigned short* __restrict__ zp) {
    constexpr int WM = BM / 4;
    constexpr int FM = WM / 16;
    constexpr int FN = BN / 16;
    constexpr int NCHR = 520;               // per ky row: 8 blocks*64 + 8 partial
    constexpr int NCH = 3 * NCHR;           // 1560 chunks of 16B
    constexpr int NCB = CIN / 32;
    constexpr int TPR = WDIM / BN;          // 2
    constexpr int NBX = HDIM * TPR;         // 512 pixel tiles
    constexpr int PER = NBX / 8;            // 64 pixel tiles per XCD
    __shared__ unsigned short s_tile[2][NCH * 8 + 256];

    const int tid = threadIdx.x;
    const int ln = tid & 63, wid = tid >> 6;
    const int ln15 = ln & 15, g = ln >> 4;

    // XCD-aware decode (bijective)
    const int b = blockIdx.x;
    const int xcd = b & 7;
    const int k = b >> 3;
    const int xt = xcd * PER + (k % PER);
    const int yt = k / PER;

    const int y0 = xt / TPR;
    const int x0 = (xt % TPR) * BN;
    const int ocb = yt * BM;

    auto stage = [&](int buf, int cb) {
#pragma unroll
        for (int c0 = 0; c0 < NCH; c0 += 256) {
            int c = c0 + tid;
            if (c < NCH) {
                int ky = c / NCHR;
                int rem = c - ky * NCHR;
                int px, gg;
                if (rem < 512) {
                    int pxb = rem >> 6;
                    int q = rem & 63;
                    gg = q >> 4;
                    px = pxb * 16 + (q & 15);
                } else {
                    int e = rem - 512;
                    gg = e >> 1;
                    px = 128 + (e & 1);
                }
                int y = y0 + ky - 1;
                int x = x0 - 1 + px;
                bool ok = ((unsigned)y < HDIM) && ((unsigned)x < WDIM);
                const unsigned short* src = ok
                    ? Xt + (size_t)(y * WDIM + x) * CIN + cb * 32 + gg * 8
                    : zp;
                gload_lds16(src, &s_tile[buf][(size_t)c * 8]);
            }
        }
    };

    f32x4 acc[FM][FN];
#pragma unroll
    for (int i = 0; i < FM; ++i)
#pragma unroll
        for (int j = 0; j < FN; ++j) acc[i][j] = f32x4{0.f, 0.f, 0.f, 0.f};

    const unsigned short* wfb = Wt + (size_t)(ocb + wid * WM + ln15) * 32 + g * 8;

    stage(0, 0);

    for (int cb = 0; cb < NCB; ++cb) {
        const int buf = cb & 1;
        __syncthreads();
        bf16x8 wreg[9][FM];
#pragma unroll
        for (int tap = 0; tap < 9; ++tap)
#pragma unroll
            for (int mf = 0; mf < FM; ++mf)
                wreg[tap][mf] = *(const bf16x8*)(wfb + (size_t)((cb * 9 + tap) * COUT + mf * 16) * 32);
        if (cb + 1 < NCB) stage(buf ^ 1, cb + 1);
        const unsigned short* st = &s_tile[buf][0];
#pragma unroll
        for (int tap = 0; tap < 9; ++tap) {
            const int ky = tap / 3, kx = tap - ky * 3;
            bf16x8 bfr[FN];
#pragma unroll
            for (int nf = 0; nf < FN; ++nf) {
                int px = kx + nf * 16 + ln15;
                int chunk = (px < 128)
                    ? ky * NCHR + ((px >> 4) << 6) + (g << 4) + (px & 15)
                    : ky * NCHR + 512 + (g << 1) + (px - 128);
                bfr[nf] = *(const bf16x8*)&st[(size_t)chunk * 8];
            }
#pragma unroll
            for (int mf = 0; mf < FM; ++mf)
#pragma unroll
                for (int nf = 0; nf < FN; ++nf)
                    acc[mf][nf] = __builtin_amdgcn_mfma_f32_16x16x32_bf16(wreg[tap][mf], bfr[nf], acc[mf][nf], 0, 0, 0);
        }
    }

    const int p0 = y0 * WDIM + x0;
#pragma unroll
    for (int nf = 0; nf < FN; ++nf) {
        const size_t p = (size_t)p0 + nf * 16 + ln15;
#pragma unroll
        for (int mf = 0; mf < FM; ++mf) {
            const int oc0 = ocb + wid * WM + mf * 16 + g * 4;
            const float4 bi = *(const float4*)(bias + oc0);
            f32x4 v = acc[mf][nf];
            float r0 = v[0] + bi.x, r1 = v[1] + bi.y, r2 = v[2] + bi.z, r3 = v[3] + bi.w;
            if (RELU) {
                r0 = fmaxf(r0, 0.f); r1 = fmaxf(r1, 0.f);
                r2 = fmaxf(r2, 0.f); r3 = fmaxf(r3, 0.f);
            }
            unsigned lo = (unsigned)f2bf(r0) | ((unsigned)f2bf(r1) << 16);
            unsigned hi = (unsigned)f2bf(r2) | ((unsigned)f2bf(r3) << 16);
            *(uint2*)(Yt + p * COUT + oc0) = uint2{lo, hi};
        }
    }
}

// ============================ MFMA conv v1 (conv3, f32 out) ============================
template <int CIN, int COUT, int BM, int BN, int WM, int WN, bool RELU>
__global__ __launch_bounds__(256, 2) void convmf_k(const unsigned short* __restrict__ Xt,
                                                   const unsigned short* __restrict__ Wt,
                                                   const float* __restrict__ bias,
                                                   float* __restrict__ Yf,
                                                   const unsigned short* __restrict__ zp) {
    constexpr int WAVES_N = BN / WN;
    constexpr int FM = WM / 16, FN = WN / 16;
    constexpr int PXT = BN + 2;
    constexpr int PXTP = BN + 6;
    constexpr int NCH = 12 * PXTP;
    constexpr int NCHP = (NCH + 255) & ~255;
    __shared__ unsigned short s_tile[NCHP * 8];

    const int tid = threadIdx.x;
    const int ln = tid & 63, wid = tid >> 6;
    const int ln15 = ln & 15, g = ln >> 4;
    const int wm_i = wid / WAVES_N, wn_i = wid % WAVES_N;

    const int per = gridDim.x >> 3;
    const int tile = (blockIdx.x & 7) * per + (blockIdx.x >> 3);

    constexpr int TPR = WDIM / BN;
    const int y0 = tile / TPR;
    const int x0 = (tile % TPR) * BN;
    const int ocb = blockIdx.y * BM;

    f32x4 acc[FM][FN];
#pragma unroll
    for (int i = 0; i < FM; ++i)
#pragma unroll
        for (int j = 0; j < FN; ++j) acc[i][j] = f32x4{0.f, 0.f, 0.f, 0.f};

    const unsigned short* wfb = Wt + (size_t)(ocb + wm_i * WM + ln15) * 32 + g * 8;

    for (int cb = 0; cb < CIN / 32; ++cb) {
        __syncthreads();
        for (int c0 = 0; c0 < NCH; c0 += 256) {
            int c = c0 + tid;
            if (c < NCH) {
                int grow = c / PXTP;
                int px = c - grow * PXTP;
                int ky = grow >> 2, gg = grow & 3;
                int y = y0 + ky - 1;
                int x = x0 - 1 + px;
                bool ok = (px < PXT) && ((unsigned)y < HDIM) && ((unsigned)x < WDIM);
                const unsigned short* src = ok
                    ? Xt + (size_t)(y * WDIM + x) * CIN + cb * 32 + gg * 8
                    : zp;
                gload_lds16(src, &s_tile[(size_t)(c0 + wid * 64) * 8]);
            }
        }
        bf16x8 wreg[9][FM];
#pragma unroll
        for (int tap = 0; tap < 9; ++tap)
#pragma unroll
            for (int mf = 0; mf < FM; ++mf)
                wreg[tap][mf] = *(const bf16x8*)(wfb + (size_t)((cb * 9 + tap) * COUT + mf * 16) * 32);
        __syncthreads();
#pragma unroll
        for (int tap = 0; tap < 9; ++tap) {
            const int ky = tap / 3, kx = tap - ky * 3;
            bf16x8 b[FN];
#pragma unroll
            for (int nf = 0; nf < FN; ++nf) {
                int slot = (ky * 4 + g) * PXTP + kx + wn_i * WN + nf * 16 + ln15;
                b[nf] = *(const bf16x8*)&s_tile[(size_t)slot * 8];
            }
#pragma unroll
            for (int mf = 0; mf < FM; ++mf)
#pragma unroll
                for (int nf = 0; nf < FN; ++nf)
                    acc[mf][nf] = __builtin_amdgcn_mfma_f32_16x16x32_bf16(wreg[tap][mf], b[nf], acc[mf][nf], 0, 0, 0);
        }
    }

    const int p0 = y0 * WDIM + x0;
#pragma unroll
    for (int nf = 0; nf < FN; ++nf) {
        const size_t p = (size_t)p0 + wn_i * WN + nf * 16 + ln15;
#pragma unroll
        for (int mf = 0; mf < FM; ++mf) {
            const int oc0 = ocb + wm_i * WM + mf * 16 + g * 4;
            const float4 bi = *(const float4*)(bias + oc0);
            f32x4 v = acc[mf][nf];
            float r0 = v[0] + bi.x, r1 = v[1] + bi.y, r2 = v[2] + bi.z, r3 = v[3] + bi.w;
            if (RELU) {
                r0 = fmaxf(r0, 0.f); r1 = fmaxf(r1, 0.f);
                r2 = fmaxf(r2, 0.f); r3 = fmaxf(r3, 0.f);
            }
            Yf[(size_t)(oc0 + 0) * HW + p] = r0;
            Yf[(size_t)(oc0 + 1) * HW + p] = r1;
            Yf[(size_t)(oc0 + 2) * HW + p] = r2;
            Yf[(size_t)(oc0 + 3) * HW + p] = r3;
        }
    }
}

// ============================ compress as MFMA GEMM from Xt ============================
__global__ __launch_bounds__(256, 2) void ccv_gemm_k(const unsigned short* __restrict__ Xt,
                                                     const unsigned short* __restrict__ wc,
                                                     const float* __restrict__ cbias,
                                                     float* __restrict__ ccv) {
    __shared__ unsigned short s_t[1024 * 8];
    const int tid = threadIdx.x;
    const int ln = tid & 63, wid = tid >> 6;
    const int ln15 = ln & 15, g = ln >> 4;
    const int per = gridDim.x >> 3;
    const int tile = (blockIdx.x & 7) * per + (blockIdx.x >> 3);
    const int p0 = tile * 256;

    f32x4 acc[2][4];
#pragma unroll
    for (int i = 0; i < 2; ++i)
#pragma unroll
        for (int j = 0; j < 4; ++j) acc[i][j] = f32x4{0.f, 0.f, 0.f, 0.f};

    for (int cb = 0; cb < 16; ++cb) {
        __syncthreads();
#pragma unroll
        for (int pass = 0; pass < 4; ++pass) {
            int c = pass * 256 + tid;
            int gg = c >> 8, px = c & 255;
            const unsigned short* src = Xt + (size_t)(p0 + px) * CDIM + cb * 32 + gg * 8;
            gload_lds16(src, &s_t[(size_t)c * 8]);
        }
        bf16x8 a[2];
#pragma unroll
        for (int mf = 0; mf < 2; ++mf)
            a[mf] = *(const bf16x8*)(wc + (size_t)((cb * 32 + mf * 16 + ln15) * 32) + g * 8);
        __syncthreads();
        bf16x8 b[4];
#pragma unroll
        for (int nf = 0; nf < 4; ++nf) {
            int slot = g * 256 + wid * 64 + nf * 16 + ln15;
            b[nf] = *(const bf16x8*)&s_t[(size_t)slot * 8];
        }
#pragma unroll
        for (int mf = 0; mf < 2; ++mf)
#pragma unroll
            for (int nf = 0; nf < 4; ++nf)
                acc[mf][nf] = __builtin_amdgcn_mfma_f32_16x16x32_bf16(a[mf], b[nf], acc[mf][nf], 0, 0, 0);
    }
#pragma unroll
    for (int nf = 0; nf < 4; ++nf) {
        const size_t p = (size_t)p0 + wid * 64 + nf * 16 + ln15;
#pragma unroll
        for (int mf = 0; mf < 2; ++mf) {
            const int oc0 = mf * 16 + g * 4;
            const float4 bi = *(const float4*)(cbias + oc0);
            f32x4 v = acc[mf][nf];
            ccv[(size_t)(oc0 + 0) * HW + p] = v[0] + bi.x;
            ccv[(size_t)(oc0 + 1) * HW + p] = v[1] + bi.y;
            ccv[(size_t)(oc0 + 2) * HW + p] = v[2] + bi.z;
            ccv[(size_t)(oc0 + 3) * HW + p] = v[3] + bi.w;
        }
    }
}

// ============================ cov / fc / combine ============================

__global__ __launch_bounds__(256) void cov_accum_k(const float* __restrict__ f,
                                                   const unsigned char* __restrict__ code,
                                                   float* __restrict__ covraw) {
    constexpr int PCH = 256;
    __shared__ float s_f[32][PCH + 1];
    const int i = blockIdx.y;
    const int p0 = blockIdx.x * PCH;
    const int t = threadIdx.x;
    for (int e = t; e < 32 * PCH; e += 256) {
        int row = e >> 8, col = e & (PCH - 1);
        int p = p0 + col;
        float m = ((code[p] >> i) & 1u) ? 1.f : 0.f;
        s_f[row][col] = f[(size_t)row * HW + p] * m;
    }
    __syncthreads();
    const int a = t >> 3;
    const int b0 = (t & 7) * 4;
    float a0 = 0.f, a1 = 0.f, a2 = 0.f, a3 = 0.f;
    for (int p = 0; p < PCH; ++p) {
        float va = s_f[a][p];
        a0 = fmaf(va, s_f[b0 + 0][p], a0);
        a1 = fmaf(va, s_f[b0 + 1][p], a1);
        a2 = fmaf(va, s_f[b0 + 2][p], a2);
        a3 = fmaf(va, s_f[b0 + 3][p], a3);
    }
    float* dst = covraw + i * 1024 + a * 32 + b0;
    atomicAdd(dst + 0, a0);
    atomicAdd(dst + 1, a1);
    atomicAdd(dst + 2, a2);
    atomicAdd(dst + 3, a3);
}

__global__ __launch_bounds__(256) void fc_k(const float* __restrict__ fcw,
                                            const float* __restrict__ fcb,
                                            const float* __restrict__ covraw,
                                            const int* __restrict__ cnt,
                                            float* __restrict__ mats) {
    const int i = blockIdx.y;
    const int wv = threadIdx.x >> 6;
    const int lane = threadIdx.x & 63;
    const int r = blockIdx.x * 4 + wv;
    const float inv = 1.f / fmaxf((float)cnt[i], 1.f);
    float acc = 0.f;
    for (int q = lane; q < 1024; q += 64)
        acc = fmaf(fcw[r * 1024 + q], covraw[i * 1024 + q] * inv, acc);
    for (int off = 32; off; off >>= 1) acc += __shfl_down(acc, off);
    if (lane == 0) mats[i * 1024 + r] = acc + fcb[r];
}

__global__ __launch_bounds__(256) void prep_small_k(const float* __restrict__ sMats,
                                                    const float* __restrict__ cMats,
                                                    const float* __restrict__ unzip_b,
                                                    const float* __restrict__ smean5,
                                                    int n,
                                                    float* __restrict__ tm5,
                                                    float* __restrict__ B5) {
    int t = blockIdx.x * 256 + threadIdx.x;
    if (t < 5 * 1024) {
        int i = t >> 10, rc = t & 1023, r = rc >> 5, c = rc & 31;
        float v;
        if (i < n) {
            float s = 0.f;
            for (int k = 0; k < 32; ++k)
                s = fmaf(sMats[i * 1024 + r * 32 + k], cMats[i * 1024 + k * 32 + c], s);
            v = s;
        } else {
            v = (r == c) ? 1.f : 0.f;
        }
        tm5[t] = v;
    } else if (t < 5 * 1024 + 5 * 512) {
        int u = t - 5 * 1024;
        int i = u >> 9, c = u & 511;
        B5[u] = unzip_b[c] + smean5[i * CDIM + c];
    }
}

// channel-split: grid (HW/256, 8); block handles 64 output channels x 256 px
__global__ __launch_bounds__(256) void final_k(const float* __restrict__ ccv,
                                               const signed char* __restrict__ fidx,
                                               const float* __restrict__ tm5,
                                               const float* __restrict__ B5,
                                               const float* __restrict__ uw,
                                               float* __restrict__ out) {
    __shared__ float s_tm[5 * 1032];
    __shared__ float s_B[5 * 68];
    const int t = threadIdx.x;
    const int c0 = blockIdx.y * 64;
    for (int e = t; e < 5 * 1024; e += 256) {
        int i = e >> 10, rc = e & 1023;
        s_tm[i * 1032 + rc] = tm5[e];
    }
    for (int e = t; e < 5 * 64; e += 256) {
        int i = e >> 6, c = e & 63;
        s_B[i * 68 + c] = B5[i * 512 + c0 + c];
    }
    __syncthreads();
    const int p = blockIdx.x * 256 + t;
    const int id = fidx[p];
    float v[32];
#pragma unroll
    for (int k = 0; k < 32; ++k) v[k] = ccv[(size_t)k * HW + p];
    float tv[32];
#pragma unroll
    for (int r = 0; r < 32; ++r) {
        float s = 0.f;
#pragma unroll
        for (int k = 0; k < 32; ++k)
            s = fmaf(s_tm[id * 1032 + r * 32 + k], v[k], s);
        tv[r] = s;
    }
    for (int c = 0; c < 64; ++c) {
        float s = s_B[id * 68 + c];
        const float* uwr = uw + (size_t)(c0 + c) * 32;
#pragma unroll
        for (int k = 0; k < 32; ++k)
            s = fmaf(uwr[k], tv[k], s);
        out[(size_t)(c0 + c) * HW + p] = s;
    }
}

// ============================ launch ============================

extern "C" void kernel_launch(void* const* d_in, const int* in_sizes, int n_in,
                              void* d_out, int out_size, void* d_ws, size_t ws_size,
                              hipStream_t stream) {
    const float* cF = (const float*)d_in[0];
    const float* sF = (const float*)d_in[1];
    const int* cmasks = (const int*)d_in[2];
    const int* smasks = (const int*)d_in[3];
    const float* snet_w1 = (const float*)d_in[4];
    const float* snet_b1 = (const float*)d_in[5];
    const float* snet_w2 = (const float*)d_in[6];
    const float* snet_b2 = (const float*)d_in[7];
    const float* snet_w3 = (const float*)d_in[8];
    const float* snet_b3 = (const float*)d_in[9];
    const float* snet_fcw = (const float*)d_in[10];
    const float* snet_fcb = (const float*)d_in[11];
    const float* cnet_w1 = (const float*)d_in[12];
    const float* cnet_b1 = (const float*)d_in[13];
    const float* cnet_w2 = (const float*)d_in[14];
    const float* cnet_b2 = (const float*)d_in[15];
    const float* cnet_w3 = (const float*)d_in[16];
    const float* cnet_b3 = (const float*)d_in[17];
    const float* cnet_fcw = (const float*)d_in[18];
    const float* cnet_fcb = (const float*)d_in[19];
    const float* compress_w = (const float*)d_in[20];
    const float* compress_b = (const float*)d_in[21];
    const float* unzip_w = (const float*)d_in[22];
    const float* unzip_b = (const float*)d_in[23];
    float* out = (float*)d_out;

    int nmC = in_sizes[2] / HW;
    int nmS = in_sizes[3] / HW;
    int n = nmC < nmS ? nmC : nmS;
    if (n > 4) n = 4;

    char* ws = (char*)d_ws;
    size_t off = 0;
    auto alloc = [&](size_t bytes) {
        size_t o = off;
        off += (bytes + 255) & ~(size_t)255;
        return o;
    };
    char* regA = ws + alloc((size_t)HW * 512 * 2);   // Xt / Y2
    char* regB = ws + alloc((size_t)HW * 256 * 2);   // Y1 / fbuf
    float* ccv  = (float*)(ws + alloc((size_t)32 * HW * 4));
    unsigned short* Wt1s = (unsigned short*)(ws + alloc((size_t)9 * 256 * 512 * 2));
    unsigned short* Wt2s = (unsigned short*)(ws + alloc((size_t)9 * 128 * 256 * 2));
    unsigned short* Wt3s = (unsigned short*)(ws + alloc((size_t)9 * 32 * 128 * 2));
    unsigned short* Wt1c = (unsigned short*)(ws + alloc((size_t)9 * 256 * 512 * 2));
    unsigned short* Wt2c = (unsigned short*)(ws + alloc((size_t)9 * 128 * 256 * 2));
    unsigned short* Wt3c = (unsigned short*)(ws + alloc((size_t)9 * 32 * 128 * 2));
    unsigned short* Wc  = (unsigned short*)(ws + alloc((size_t)32 * 512 * 2));
    unsigned char* ccode = (unsigned char*)(ws + alloc(HW));
    unsigned char* scode = (unsigned char*)(ws + alloc(HW));
    signed char* cidx = (signed char*)(ws + alloc(HW));
    signed char* sidx = (signed char*)(ws + alloc(HW));
    signed char* fidx = (signed char*)(ws + alloc(HW));
    int*   cnt    = (int*)(ws + alloc(8 * 4));
    float* cmean5 = (float*)(ws + alloc(5 * CDIM * 4));
    float* smean5 = (float*)(ws + alloc(5 * CDIM * 4));
    float* covraw = (float*)(ws + alloc(8 * 1024 * 4));
    float* sMats  = (float*)(ws + alloc(4 * 1024 * 4));
    float* cMats  = (float*)(ws + alloc(4 * 1024 * 4));
    float* tm5    = (float*)(ws + alloc(5 * 1024 * 4));
    float* B5     = (float*)(ws + alloc(5 * 512 * 4));
    float* zpf    = (float*)(ws + alloc(256));
    (void)ws_size; (void)n_in; (void)out_size;

    unsigned short* Xt = (unsigned short*)regA;
    unsigned short* Y2 = (unsigned short*)regA;   // overwrites Xt only at conv2 (Xt dead)
    unsigned short* Y1 = (unsigned short*)regB;
    float*          fbuf = (float*)regB;
    const unsigned short* zp = (const unsigned short*)zpf;

    // ---- stage 0: fused prep (zero + all weight transforms) + masks/means/idx ----
    prep_all_k<<<11905, 256, 0, stream>>>(cnt, covraw, zpf, compress_w, Wc,
                                          snet_w1, Wt1s, snet_w2, Wt2s, snet_w3, Wt3s,
                                          cnet_w1, Wt1c, cnet_w2, Wt2c, cnet_w3, Wt3c);
    pack_masks_k<<<HW / 256, 256, 0, stream>>>(cmasks, smasks, n, ccode, scode, cnt);
    masked_means_k<<<2 * CDIM, 256, 0, stream>>>(cF, sF, ccode, scode, cnt, cmean5, smean5);
    idx_maps_k<<<HW / 256, 256, 0, stream>>>(ccode, scode, cnt, n, cidx, sidx, fidx);

    // ---- snet ----
    trans_in_k<<<dim3(HW / 64, 8), 256, 0, stream>>>(sF, smean5, sidx, Xt);
    convmf2_k<512, 256, 128, 128, true ><<<1024, 256, 0, stream>>>(Xt, Wt1s, snet_b1, Y1, zp);
    convmf2_k<256, 128, 128, 128, true ><<<512, 256, 0, stream>>>(Y1, Wt2s, snet_b2, Y2, zp);
    convmf_k<128, 32,  32,  256, 32, 64, false><<<dim3(256, 1), 256, 0, stream>>>(Y2, Wt3s, snet_b3, fbuf, zp);
    cov_accum_k<<<dim3(HW / 256, n), 256, 0, stream>>>(fbuf, scode, covraw);
    fc_k<<<dim3(256, n), 256, 0, stream>>>(snet_fcw, snet_fcb, covraw, cnt + 4, sMats);

    // ---- cnet ----
    trans_in_k<<<dim3(HW / 64, 8), 256, 0, stream>>>(cF, cmean5, cidx, Xt);
    ccv_gemm_k<<<HW / 256, 256, 0, stream>>>(Xt, Wc, compress_b, ccv);   // while Xt alive
    convmf2_k<512, 256, 128, 128, true ><<<1024, 256, 0, stream>>>(Xt, Wt1c, cnet_b1, Y1, zp);
    convmf2_k<256, 128, 128, 128, true ><<<512, 256, 0, stream>>>(Y1, Wt2c, cnet_b2, Y2, zp);
    convmf_k<128, 32,  32,  256, 32, 64, false><<<dim3(256, 1), 256, 0, stream>>>(Y2, Wt3c, cnet_b3, fbuf, zp);
    cov_accum_k<<<dim3(HW / 256, n), 256, 0, stream>>>(fbuf, ccode, covraw + 4 * 1024);
    fc_k<<<dim3(256, n), 256, 0, stream>>>(cnet_fcw, cnet_fcb, covraw + 4 * 1024, cnt, cMats);

    // ---- combine ----
    prep_small_k<<<30, 256, 0, stream>>>(sMats, cMats, unzip_b, smean5, n, tm5, B5);
    final_k<<<dim3(HW / 256, 8), 256, 0, stream>>>(ccv, fidx, tm5, B5, unzip_w, out);
}

// Round 14
// 841.550 us; speedup vs baseline: 1.4783x; 1.0484x over previous
//
#include <hip/hip_runtime.h>

#define HDIM 256
#define WDIM 256
#define HW   65536
#define CDIM 512

using bf16x8 = __attribute__((ext_vector_type(8))) short;
using f32x4  = __attribute__((ext_vector_type(4))) float;

__device__ __forceinline__ unsigned short f2bf(float f) {
    unsigned u = __builtin_bit_cast(unsigned, f);
    u += 0x7FFFu + ((u >> 16) & 1u);          // RNE
    return (unsigned short)(u >> 16);
}

__device__ __forceinline__ void gload_lds16(const void* g, void* l) {
    __builtin_amdgcn_global_load_lds((const __attribute__((address_space(1))) unsigned int*)g,
                                     (__attribute__((address_space(3))) unsigned int*)l, 16, 0, 0);
}

// ============================ fused prep (zero + all weight transforms) ============

__device__ __forceinline__ void wtrans_one(const float* __restrict__ w,
                                           unsigned short* __restrict__ wt,
                                           int COUT, int CIN, int t) {
    int oc = t / (CIN * 9);
    int rem = t - oc * (CIN * 9);
    int ci = rem / 9;
    int tap = rem - ci * 9;
    wt[(size_t)(((ci >> 5) * 9 + tap) * COUT + oc) * 32 + (ci & 31)] = f2bf(w[t]);
}

__global__ __launch_bounds__(256) void prep_all_k(int* __restrict__ cnt,
                                                  float* __restrict__ covraw,
                                                  float* __restrict__ zp,
                                                  const float* __restrict__ cw, unsigned short* __restrict__ wc,
                                                  const float* __restrict__ s1, unsigned short* __restrict__ W1s,
                                                  const float* __restrict__ s2, unsigned short* __restrict__ W2s,
                                                  const float* __restrict__ s3, unsigned short* __restrict__ W3s,
                                                  const float* __restrict__ c1, unsigned short* __restrict__ W1c,
                                                  const float* __restrict__ c2, unsigned short* __restrict__ W2c,
                                                  const float* __restrict__ c3, unsigned short* __restrict__ W3c) {
    int t = blockIdx.x * 256 + threadIdx.x;
    if (t < 8264) {
        if (t < 8) cnt[t] = 0;
        else if (t < 8200) covraw[t - 8] = 0.f;
        else if (t < 8264) zp[t - 8200] = 0.f;
        return;
    }
    t -= 8264;
    if (t < 16384) {
        int oc = t >> 9, ci = t & 511;
        wc[(size_t)((ci >> 5) * 32 + oc) * 32 + (ci & 31)] = f2bf(cw[t]);
        return;
    }
    t -= 16384;
    if (t < 1179648) { wtrans_one(s1, W1s, 256, 512, t); return; }
    t -= 1179648;
    if (t < 294912)  { wtrans_one(s2, W2s, 128, 256, t); return; }
    t -= 294912;
    if (t < 36864)   { wtrans_one(s3, W3s, 32, 128, t); return; }
    t -= 36864;
    if (t < 1179648) { wtrans_one(c1, W1c, 256, 512, t); return; }
    t -= 1179648;
    if (t < 294912)  { wtrans_one(c2, W2c, 128, 256, t); return; }
    t -= 294912;
    if (t < 36864)   { wtrans_one(c3, W3c, 32, 128, t); return; }
}

// ============================ small kernels ============================

__global__ __launch_bounds__(256) void pack_masks_k(const int* __restrict__ cm,
                                                    const int* __restrict__ sm,
                                                    int n,
                                                    unsigned char* __restrict__ ccode,
                                                    unsigned char* __restrict__ scode,
                                                    int* __restrict__ cnt) {
    int p = blockIdx.x * 256 + threadIdx.x;
    unsigned cc = 0, sc = 0;
    for (int i = 0; i < n; ++i) {
        if (cm[i * HW + p] != 0) cc |= (1u << i);
        if (sm[i * HW + p] != 0) sc |= (1u << i);
    }
    ccode[p] = (unsigned char)cc;
    scode[p] = (unsigned char)sc;
    int lane = threadIdx.x & 63;
    for (int i = 0; i < n; ++i) {
        unsigned long long bc = __ballot((cc >> i) & 1);
        unsigned long long bs = __ballot((sc >> i) & 1);
        if (lane == 0) {
            atomicAdd(&cnt[i],     (int)__popcll(bc));
            atomicAdd(&cnt[4 + i], (int)__popcll(bs));
        }
    }
}

__global__ __launch_bounds__(256) void masked_means_k(const float* __restrict__ cF,
                                                      const float* __restrict__ sF,
                                                      const unsigned char* __restrict__ ccode,
                                                      const unsigned char* __restrict__ scode,
                                                      const int* __restrict__ cnt,
                                                      float* __restrict__ cmean5,
                                                      float* __restrict__ smean5) {
    int b = blockIdx.x;
    const float* x; const unsigned char* code; const int* cn; float* mout;
    if (b < CDIM) { x = cF; code = ccode; cn = cnt;     mout = cmean5; }
    else          { x = sF; code = scode; cn = cnt + 4; mout = smean5; b -= CDIM; }
    const int c = b;
    const int t = threadIdx.x;
    const float4* x4 = (const float4*)(x + (size_t)c * HW);
    const unsigned* cd4 = (const unsigned*)code;
    float s0 = 0.f, s1 = 0.f, s2 = 0.f, s3 = 0.f;
    for (int i = t; i < HW / 4; i += 256) {
        float4 v = x4[i];
        unsigned cd = cd4[i];
        float vv;
        vv = v.x;
        if (cd & 0x01u) s0 += vv;
        if (cd & 0x02u) s1 += vv;
        if (cd & 0x04u) s2 += vv;
        if (cd & 0x08u) s3 += vv;
        vv = v.y;
        if (cd & 0x0100u) s0 += vv;
        if (cd & 0x0200u) s1 += vv;
        if (cd & 0x0400u) s2 += vv;
        if (cd & 0x0800u) s3 += vv;
        vv = v.z;
        if (cd & 0x010000u) s0 += vv;
        if (cd & 0x020000u) s1 += vv;
        if (cd & 0x040000u) s2 += vv;
        if (cd & 0x080000u) s3 += vv;
        vv = v.w;
        if (cd & 0x01000000u) s0 += vv;
        if (cd & 0x02000000u) s1 += vv;
        if (cd & 0x04000000u) s2 += vv;
        if (cd & 0x08000000u) s3 += vv;
    }
    __shared__ float red[4][256];
    red[0][t] = s0; red[1][t] = s1; red[2][t] = s2; red[3][t] = s3;
    __syncthreads();
    for (int off = 128; off; off >>= 1) {
        if (t < off) {
            red[0][t] += red[0][t + off];
            red[1][t] += red[1][t + off];
            red[2][t] += red[2][t + off];
            red[3][t] += red[3][t + off];
        }
        __syncthreads();
    }
    if (t < 4) mout[t * CDIM + c] = red[t][0] / fmaxf((float)cn[t], 1.f);
    if (t == 4) mout[4 * CDIM + c] = 0.f;
}

__global__ __launch_bounds__(256) void idx_maps_k(const unsigned char* __restrict__ ccode,
                                                  const unsigned char* __restrict__ scode,
                                                  const int* __restrict__ cnt, int n,
                                                  signed char* __restrict__ cidx,
                                                  signed char* __restrict__ sidx,
                                                  signed char* __restrict__ fidx) {
    int p = blockIdx.x * 256 + threadIdx.x;
    int cc = ccode[p], sc = scode[p];
    int ci = 4, si = 4, fi = 4;
    for (int i = 0; i < n; ++i) {
        bool cv = cnt[i] >= 10;
        bool sv = cnt[4 + i] >= 10;
        if (((cc >> i) & 1) && cv) ci = i;
        if (((sc >> i) & 1) && sv) si = i;
        if (((cc >> i) & 1) && cv && sv) fi = i;
    }
    cidx[p] = (signed char)ci;
    sidx[p] = (signed char)si;
    fidx[p] = (signed char)fi;
}

__global__ __launch_bounds__(256) void trans_in_k(const float* __restrict__ X,
                                                  const float* __restrict__ mean5,
                                                  const signed char* __restrict__ idx5,
                                                  unsigned short* __restrict__ Xt) {
    __shared__ unsigned s32[64 * 33];
    const int tid = threadIdx.x;
    const int p0 = blockIdx.x * 64;
    const int c0 = blockIdx.y * 64;
    const int cpair = tid >> 3;
    const int q = tid & 7;
    const int ch0 = c0 + cpair * 2;
    const float* X0 = X + (size_t)ch0 * HW;
    const float* X1 = X0 + HW;
#pragma unroll
    for (int k = 0; k < 2; ++k) {
        int px0 = (q + k * 8) * 4;
        float4 va = *(const float4*)(X0 + p0 + px0);
        float4 vb = *(const float4*)(X1 + p0 + px0);
        int id4 = *(const int*)(idx5 + p0 + px0);
        float a[4] = {va.x, va.y, va.z, va.w};
        float b[4] = {vb.x, vb.y, vb.z, vb.w};
#pragma unroll
        for (int j = 0; j < 4; ++j) {
            int id = (id4 >> (8 * j)) & 0xFF;
            const float* mr = mean5 + id * CDIM;
            unsigned u = (unsigned)f2bf(a[j] - mr[ch0])
                       | ((unsigned)f2bf(b[j] - mr[ch0 + 1]) << 16);
            s32[(px0 + j) * 33 + cpair] = u;
        }
    }
    __syncthreads();
    const int px = tid >> 2, h = tid & 3;
    const unsigned* rp = &s32[px * 33 + h * 8];
    uint4 u0 = *(const uint4*)(rp);
    uint4 u1 = *(const uint4*)(rp + 4);
    unsigned short* dst = Xt + (size_t)(p0 + px) * CDIM + c0 + h * 16;
    *(uint4*)dst = u0;
    *(uint4*)(dst + 8) = u1;
}

// ============================ MFMA conv v2 (conflict-free LDS; dual-net batched) ======
// Grid = 2*NBNET (or NBNET for single-net call); blocks >= NBNET take the b-set.
template <int CIN, int COUT, int BM, int BN, bool RELU>
__global__ __launch_bounds__(256, 2) void convmf2_k(const unsigned short* __restrict__ Xt0,
                                                    const unsigned short* __restrict__ Wt0,
                                                    const float* __restrict__ bias0,
                                                    unsigned short* __restrict__ Yt0,
                                                    const unsigned short* __restrict__ Xt1,
                                                    const unsigned short* __restrict__ Wt1,
                                                    const float* __restrict__ bias1,
                                                    unsigned short* __restrict__ Yt1,
                                                    const unsigned short* __restrict__ zp) {
    constexpr int WM = BM / 4;
    constexpr int FM = WM / 16;
    constexpr int FN = BN / 16;
    constexpr int NCHR = 520;
    constexpr int NCH = 3 * NCHR;
    constexpr int NCB = CIN / 32;
    constexpr int TPR = WDIM / BN;          // 2
    constexpr int NBX = HDIM * TPR;         // 512
    constexpr int PER = NBX / 8;
    constexpr int GRIDY = COUT / BM;
    constexpr int NBNET = NBX * GRIDY;
    __shared__ unsigned short s_tile[2][NCH * 8 + 256];

    const int tid = threadIdx.x;
    const int ln = tid & 63, wid = tid >> 6;
    const int ln15 = ln & 15, g = ln >> 4;

    int b = blockIdx.x;
    const bool net1 = (b >= NBNET);
    if (net1) b -= NBNET;
    const unsigned short* Xt = net1 ? Xt1 : Xt0;
    const unsigned short* Wt = net1 ? Wt1 : Wt0;
    const float* bias = net1 ? bias1 : bias0;
    unsigned short* Yt = net1 ? Yt1 : Yt0;

    const int xcd = b & 7;
    const int k = b >> 3;
    const int xt = xcd * PER + (k % PER);
    const int yt = k / PER;

    const int y0 = xt / TPR;
    const int x0 = (xt % TPR) * BN;
    const int ocb = yt * BM;

    auto stage = [&](int buf, int cb) {
#pragma unroll
        for (int c0 = 0; c0 < NCH; c0 += 256) {
            int c = c0 + tid;
            if (c < NCH) {
                int ky = c / NCHR;
                int rem = c - ky * NCHR;
                int px, gg;
                if (rem < 512) {
                    int pxb = rem >> 6;
                    int q = rem & 63;
                    gg = q >> 4;
                    px = pxb * 16 + (q & 15);
                } else {
                    int e = rem - 512;
                    gg = e >> 1;
                    px = 128 + (e & 1);
                }
                int y = y0 + ky - 1;
                int x = x0 - 1 + px;
                bool ok = ((unsigned)y < HDIM) && ((unsigned)x < WDIM);
                const unsigned short* src = ok
                    ? Xt + (size_t)(y * WDIM + x) * CIN + cb * 32 + gg * 8
                    : zp;
                gload_lds16(src, &s_tile[buf][(size_t)c * 8]);
            }
        }
    };

    f32x4 acc[FM][FN];
#pragma unroll
    for (int i = 0; i < FM; ++i)
#pragma unroll
        for (int j = 0; j < FN; ++j) acc[i][j] = f32x4{0.f, 0.f, 0.f, 0.f};

    const unsigned short* wfb = Wt + (size_t)(ocb + wid * WM + ln15) * 32 + g * 8;

    stage(0, 0);

    for (int cb = 0; cb < NCB; ++cb) {
        const int buf = cb & 1;
        __syncthreads();
        bf16x8 wreg[9][FM];
#pragma unroll
        for (int tap = 0; tap < 9; ++tap)
#pragma unroll
            for (int mf = 0; mf < FM; ++mf)
                wreg[tap][mf] = *(const bf16x8*)(wfb + (size_t)((cb * 9 + tap) * COUT + mf * 16) * 32);
        if (cb + 1 < NCB) stage(buf ^ 1, cb + 1);
        const unsigned short* st = &s_tile[buf][0];
#pragma unroll
        for (int tap = 0; tap < 9; ++tap) {
            const int ky = tap / 3, kx = tap - ky * 3;
            bf16x8 bfr[FN];
#pragma unroll
            for (int nf = 0; nf < FN; ++nf) {
                int px = kx + nf * 16 + ln15;
                int chunk = (px < 128)
                    ? ky * NCHR + ((px >> 4) << 6) + (g << 4) + (px & 15)
                    : ky * NCHR + 512 + (g << 1) + (px - 128);
                bfr[nf] = *(const bf16x8*)&st[(size_t)chunk * 8];
            }
#pragma unroll
            for (int mf = 0; mf < FM; ++mf)
#pragma unroll
                for (int nf = 0; nf < FN; ++nf)
                    acc[mf][nf] = __builtin_amdgcn_mfma_f32_16x16x32_bf16(wreg[tap][mf], bfr[nf], acc[mf][nf], 0, 0, 0);
        }
    }

    const int p0 = y0 * WDIM + x0;
#pragma unroll
    for (int nf = 0; nf < FN; ++nf) {
        const size_t p = (size_t)p0 + nf * 16 + ln15;
#pragma unroll
        for (int mf = 0; mf < FM; ++mf) {
            const int oc0 = ocb + wid * WM + mf * 16 + g * 4;
            const float4 bi = *(const float4*)(bias + oc0);
            f32x4 v = acc[mf][nf];
            float r0 = v[0] + bi.x, r1 = v[1] + bi.y, r2 = v[2] + bi.z, r3 = v[3] + bi.w;
            if (RELU) {
                r0 = fmaxf(r0, 0.f); r1 = fmaxf(r1, 0.f);
                r2 = fmaxf(r2, 0.f); r3 = fmaxf(r3, 0.f);
            }
            unsigned lo = (unsigned)f2bf(r0) | ((unsigned)f2bf(r1) << 16);
            unsigned hi = (unsigned)f2bf(r2) | ((unsigned)f2bf(r3) << 16);
            *(uint2*)(Yt + p * COUT + oc0) = uint2{lo, hi};
        }
    }
}

// ============================ MFMA conv v1 (conv3, f32 out; dual-net batched) ======
template <int CIN, int COUT, int BM, int BN, int WM, int WN, bool RELU>
__global__ __launch_bounds__(256, 2) void convmf_k(const unsigned short* __restrict__ Xt0,
                                                   const unsigned short* __restrict__ Wt0,
                                                   const float* __restrict__ bias0,
                                                   float* __restrict__ Yf0,
                                                   const unsigned short* __restrict__ Xt1,
                                                   const unsigned short* __restrict__ Wt1,
                                                   const float* __restrict__ bias1,
                                                   float* __restrict__ Yf1,
                                                   const unsigned short* __restrict__ zp) {
    constexpr int WAVES_N = BN / WN;
    constexpr int FM = WM / 16, FN = WN / 16;
    constexpr int PXT = BN + 2;
    constexpr int PXTP = BN + 6;
    constexpr int NCH = 12 * PXTP;
    constexpr int NCHP = (NCH + 255) & ~255;
    constexpr int TPR = WDIM / BN;          // 1 for BN=256
    constexpr int NBNET = HDIM * TPR;       // 256
    constexpr int PER = NBNET / 8;
    __shared__ unsigned short s_tile[NCHP * 8];

    const int tid = threadIdx.x;
    const int ln = tid & 63, wid = tid >> 6;
    const int ln15 = ln & 15, g = ln >> 4;
    const int wm_i = wid / WAVES_N, wn_i = wid % WAVES_N;

    int b = blockIdx.x;
    const bool net1 = (b >= NBNET);
    if (net1) b -= NBNET;
    const unsigned short* Xt = net1 ? Xt1 : Xt0;
    const unsigned short* Wt = net1 ? Wt1 : Wt0;
    const float* bias = net1 ? bias1 : bias0;
    float* Yf = net1 ? Yf1 : Yf0;

    const int tile = (b & 7) * PER + (b >> 3);
    const int y0 = tile / TPR;
    const int x0 = (tile % TPR) * BN;
    const int ocb = 0;                      // COUT == BM for conv3

    f32x4 acc[FM][FN];
#pragma unroll
    for (int i = 0; i < FM; ++i)
#pragma unroll
        for (int j = 0; j < FN; ++j) acc[i][j] = f32x4{0.f, 0.f, 0.f, 0.f};

    const unsigned short* wfb = Wt + (size_t)(ocb + wm_i * WM + ln15) * 32 + g * 8;

    for (int cb = 0; cb < CIN / 32; ++cb) {
        __syncthreads();
        for (int c0 = 0; c0 < NCH; c0 += 256) {
            int c = c0 + tid;
            if (c < NCH) {
                int grow = c / PXTP;
                int px = c - grow * PXTP;
                int ky = grow >> 2, gg = grow & 3;
                int y = y0 + ky - 1;
                int x = x0 - 1 + px;
                bool ok = (px < PXT) && ((unsigned)y < HDIM) && ((unsigned)x < WDIM);
                const unsigned short* src = ok
                    ? Xt + (size_t)(y * WDIM + x) * CIN + cb * 32 + gg * 8
                    : zp;
                gload_lds16(src, &s_tile[(size_t)(c0 + wid * 64) * 8]);
            }
        }
        bf16x8 wreg[9][FM];
#pragma unroll
        for (int tap = 0; tap < 9; ++tap)
#pragma unroll
            for (int mf = 0; mf < FM; ++mf)
                wreg[tap][mf] = *(const bf16x8*)(wfb + (size_t)((cb * 9 + tap) * COUT + mf * 16) * 32);
        __syncthreads();
#pragma unroll
        for (int tap = 0; tap < 9; ++tap) {
            const int ky = tap / 3, kx = tap - ky * 3;
            bf16x8 bb[FN];
#pragma unroll
            for (int nf = 0; nf < FN; ++nf) {
                int slot = (ky * 4 + g) * PXTP + kx + wn_i * WN + nf * 16 + ln15;
                bb[nf] = *(const bf16x8*)&s_tile[(size_t)slot * 8];
            }
#pragma unroll
            for (int mf = 0; mf < FM; ++mf)
#pragma unroll
                for (int nf = 0; nf < FN; ++nf)
                    acc[mf][nf] = __builtin_amdgcn_mfma_f32_16x16x32_bf16(wreg[tap][mf], bb[nf], acc[mf][nf], 0, 0, 0);
        }
    }

    const int p0 = y0 * WDIM + x0;
#pragma unroll
    for (int nf = 0; nf < FN; ++nf) {
        const size_t p = (size_t)p0 + wn_i * WN + nf * 16 + ln15;
#pragma unroll
        for (int mf = 0; mf < FM; ++mf) {
            const int oc0 = ocb + wm_i * WM + mf * 16 + g * 4;
            const float4 bi = *(const float4*)(bias + oc0);
            f32x4 v = acc[mf][nf];
            float r0 = v[0] + bi.x, r1 = v[1] + bi.y, r2 = v[2] + bi.z, r3 = v[3] + bi.w;
            if (RELU) {
                r0 = fmaxf(r0, 0.f); r1 = fmaxf(r1, 0.f);
                r2 = fmaxf(r2, 0.f); r3 = fmaxf(r3, 0.f);
            }
            Yf[(size_t)(oc0 + 0) * HW + p] = r0;
            Yf[(size_t)(oc0 + 1) * HW + p] = r1;
            Yf[(size_t)(oc0 + 2) * HW + p] = r2;
            Yf[(size_t)(oc0 + 3) * HW + p] = r3;
        }
    }
}

// ============================ compress as MFMA GEMM from Xt ============================
__global__ __launch_bounds__(256, 2) void ccv_gemm_k(const unsigned short* __restrict__ Xt,
                                                     const unsigned short* __restrict__ wc,
                                                     const float* __restrict__ cbias,
                                                     float* __restrict__ ccv) {
    __shared__ unsigned short s_t[1024 * 8];
    const int tid = threadIdx.x;
    const int ln = tid & 63, wid = tid >> 6;
    const int ln15 = ln & 15, g = ln >> 4;
    const int per = gridDim.x >> 3;
    const int tile = (blockIdx.x & 7) * per + (blockIdx.x >> 3);
    const int p0 = tile * 256;

    f32x4 acc[2][4];
#pragma unroll
    for (int i = 0; i < 2; ++i)
#pragma unroll
        for (int j = 0; j < 4; ++j) acc[i][j] = f32x4{0.f, 0.f, 0.f, 0.f};

    for (int cb = 0; cb < 16; ++cb) {
        __syncthreads();
#pragma unroll
        for (int pass = 0; pass < 4; ++pass) {
            int c = pass * 256 + tid;
            int gg = c >> 8, px = c & 255;
            const unsigned short* src = Xt + (size_t)(p0 + px) * CDIM + cb * 32 + gg * 8;
            gload_lds16(src, &s_t[(size_t)c * 8]);
        }
        bf16x8 a[2];
#pragma unroll
        for (int mf = 0; mf < 2; ++mf)
            a[mf] = *(const bf16x8*)(wc + (size_t)((cb * 32 + mf * 16 + ln15) * 32) + g * 8);
        __syncthreads();
        bf16x8 b[4];
#pragma unroll
        for (int nf = 0; nf < 4; ++nf) {
            int slot = g * 256 + wid * 64 + nf * 16 + ln15;
            b[nf] = *(const bf16x8*)&s_t[(size_t)slot * 8];
        }
#pragma unroll
        for (int mf = 0; mf < 2; ++mf)
#pragma unroll
            for (int nf = 0; nf < 4; ++nf)
                acc[mf][nf] = __builtin_amdgcn_mfma_f32_16x16x32_bf16(a[mf], b[nf], acc[mf][nf], 0, 0, 0);
    }
#pragma unroll
    for (int nf = 0; nf < 4; ++nf) {
        const size_t p = (size_t)p0 + wid * 64 + nf * 16 + ln15;
#pragma unroll
        for (int mf = 0; mf < 2; ++mf) {
            const int oc0 = mf * 16 + g * 4;
            const float4 bi = *(const float4*)(cbias + oc0);
            f32x4 v = acc[mf][nf];
            ccv[(size_t)(oc0 + 0) * HW + p] = v[0] + bi.x;
            ccv[(size_t)(oc0 + 1) * HW + p] = v[1] + bi.y;
            ccv[(size_t)(oc0 + 2) * HW + p] = v[2] + bi.z;
            ccv[(size_t)(oc0 + 3) * HW + p] = v[3] + bi.w;
        }
    }
}

// ============================ cov / fc / combine (dual-net via blockIdx.z) ============

__global__ __launch_bounds__(256) void cov_accum_k(const float* __restrict__ f0,
                                                   const unsigned char* __restrict__ code0,
                                                   float* __restrict__ cov0,
                                                   const float* __restrict__ f1,
                                                   const unsigned char* __restrict__ code1,
                                                   float* __restrict__ cov1) {
    constexpr int PCH = 256;
    __shared__ float s_f[32][PCH + 1];
    const bool net1 = blockIdx.z != 0;
    const float* f = net1 ? f1 : f0;
    const unsigned char* code = net1 ? code1 : code0;
    float* covraw = net1 ? cov1 : cov0;
    const int i = blockIdx.y;
    const int p0 = blockIdx.x * PCH;
    const int t = threadIdx.x;
    for (int e = t; e < 32 * PCH; e += 256) {
        int row = e >> 8, col = e & (PCH - 1);
        int p = p0 + col;
        float m = ((code[p] >> i) & 1u) ? 1.f : 0.f;
        s_f[row][col] = f[(size_t)row * HW + p] * m;
    }
    __syncthreads();
    const int a = t >> 3;
    const int b0 = (t & 7) * 4;
    float a0 = 0.f, a1 = 0.f, a2 = 0.f, a3 = 0.f;
    for (int p = 0; p < PCH; ++p) {
        float va = s_f[a][p];
        a0 = fmaf(va, s_f[b0 + 0][p], a0);
        a1 = fmaf(va, s_f[b0 + 1][p], a1);
        a2 = fmaf(va, s_f[b0 + 2][p], a2);
        a3 = fmaf(va, s_f[b0 + 3][p], a3);
    }
    float* dst = covraw + i * 1024 + a * 32 + b0;
    atomicAdd(dst + 0, a0);
    atomicAdd(dst + 1, a1);
    atomicAdd(dst + 2, a2);
    atomicAdd(dst + 3, a3);
}

__global__ __launch_bounds__(256) void fc_k(const float* __restrict__ fcw0,
                                            const float* __restrict__ fcb0,
                                            const float* __restrict__ cov0,
                                            const int* __restrict__ cnt0,
                                            float* __restrict__ mats0,
                                            const float* __restrict__ fcw1,
                                            const float* __restrict__ fcb1,
                                            const float* __restrict__ cov1,
                                            const int* __restrict__ cnt1,
                                            float* __restrict__ mats1) {
    const bool net1 = blockIdx.z != 0;
    const float* fcw = net1 ? fcw1 : fcw0;
    const float* fcb = net1 ? fcb1 : fcb0;
    const float* covraw = net1 ? cov1 : cov0;
    const int* cnt = net1 ? cnt1 : cnt0;
    float* mats = net1 ? mats1 : mats0;
    const int i = blockIdx.y;
    const int wv = threadIdx.x >> 6;
    const int lane = threadIdx.x & 63;
    const int r = blockIdx.x * 4 + wv;
    const float inv = 1.f / fmaxf((float)cnt[i], 1.f);
    float acc = 0.f;
    for (int q = lane; q < 1024; q += 64)
        acc = fmaf(fcw[r * 1024 + q], covraw[i * 1024 + q] * inv, acc);
    for (int off = 32; off; off >>= 1) acc += __shfl_down(acc, off);
    if (lane == 0) mats[i * 1024 + r] = acc + fcb[r];
}

__global__ __launch_bounds__(256) void prep_small_k(const float* __restrict__ sMats,
                                                    const float* __restrict__ cMats,
                                                    const float* __restrict__ unzip_b,
                                                    const float* __restrict__ smean5,
                                                    int n,
                                                    float* __restrict__ tm5,
                                                    float* __restrict__ B5) {
    int t = blockIdx.x * 256 + threadIdx.x;
    if (t < 5 * 1024) {
        int i = t >> 10, rc = t & 1023, r = rc >> 5, c = rc & 31;
        float v;
        if (i < n) {
            float s = 0.f;
            for (int k = 0; k < 32; ++k)
                s = fmaf(sMats[i * 1024 + r * 32 + k], cMats[i * 1024 + k * 32 + c], s);
            v = s;
        } else {
            v = (r == c) ? 1.f : 0.f;
        }
        tm5[t] = v;
    } else if (t < 5 * 1024 + 5 * 512) {
        int u = t - 5 * 1024;
        int i = u >> 9, c = u & 511;
        B5[u] = unzip_b[c] + smean5[i * CDIM + c];
    }
}

// channel-split final: grid (HW/256, 8)
__global__ __launch_bounds__(256) void final_k(const float* __restrict__ ccv,
                                               const signed char* __restrict__ fidx,
                                               const float* __restrict__ tm5,
                                               const float* __restrict__ B5,
                                               const float* __restrict__ uw,
                                               float* __restrict__ out) {
    __shared__ float s_tm[5 * 1032];
    __shared__ float s_B[5 * 68];
    const int t = threadIdx.x;
    const int c0 = blockIdx.y * 64;
    for (int e = t; e < 5 * 1024; e += 256) {
        int i = e >> 10, rc = e & 1023;
        s_tm[i * 1032 + rc] = tm5[e];
    }
    for (int e = t; e < 5 * 64; e += 256) {
        int i = e >> 6, c = e & 63;
        s_B[i * 68 + c] = B5[i * 512 + c0 + c];
    }
    __syncthreads();
    const int p = blockIdx.x * 256 + t;
    const int id = fidx[p];
    float v[32];
#pragma unroll
    for (int k = 0; k < 32; ++k) v[k] = ccv[(size_t)k * HW + p];
    float tv[32];
#pragma unroll
    for (int r = 0; r < 32; ++r) {
        float s = 0.f;
#pragma unroll
        for (int k = 0; k < 32; ++k)
            s = fmaf(s_tm[id * 1032 + r * 32 + k], v[k], s);
        tv[r] = s;
    }
    for (int c = 0; c < 64; ++c) {
        float s = s_B[id * 68 + c];
        const float* uwr = uw + (size_t)(c0 + c) * 32;
#pragma unroll
        for (int k = 0; k < 32; ++k)
            s = fmaf(uwr[k], tv[k], s);
        out[(size_t)(c0 + c) * HW + p] = s;
    }
}

// ============================ launch ============================

extern "C" void kernel_launch(void* const* d_in, const int* in_sizes, int n_in,
                              void* d_out, int out_size, void* d_ws, size_t ws_size,
                              hipStream_t stream) {
    const float* cF = (const float*)d_in[0];
    const float* sF = (const float*)d_in[1];
    const int* cmasks = (const int*)d_in[2];
    const int* smasks = (const int*)d_in[3];
    const float* snet_w1 = (const float*)d_in[4];
    const float* snet_b1 = (const float*)d_in[5];
    const float* snet_w2 = (const float*)d_in[6];
    const float* snet_b2 = (const float*)d_in[7];
    const float* snet_w3 = (const float*)d_in[8];
    const float* snet_b3 = (const float*)d_in[9];
    const float* snet_fcw = (const float*)d_in[10];
    const float* snet_fcb = (const float*)d_in[11];
    const float* cnet_w1 = (const float*)d_in[12];
    const float* cnet_b1 = (const float*)d_in[13];
    const float* cnet_w2 = (const float*)d_in[14];
    const float* cnet_b2 = (const float*)d_in[15];
    const float* cnet_w3 = (const float*)d_in[16];
    const float* cnet_b3 = (const float*)d_in[17];
    const float* cnet_fcw = (const float*)d_in[18];
    const float* cnet_fcb = (const float*)d_in[19];
    const float* compress_w = (const float*)d_in[20];
    const float* compress_b = (const float*)d_in[21];
    const float* unzip_w = (const float*)d_in[22];
    const float* unzip_b = (const float*)d_in[23];
    float* out = (float*)d_out;

    int nmC = in_sizes[2] / HW;
    int nmS = in_sizes[3] / HW;
    int n = nmC < nmS ? nmC : nmS;
    if (n > 4) n = 4;

    char* ws = (char*)d_ws;
    size_t off = 0;
    auto alloc = [&](size_t bytes) {
        size_t o = off;
        off += (bytes + 255) & ~(size_t)255;
        return o;
    };
    // regA: Xt [HW][512]bf16; later Y2s [HW][128] @0 and Y2c @ +16.8MB
    char* regA = ws + alloc((size_t)HW * 512 * 2);
    // B1: Y1s [HW][256]bf16; later fbs [32][HW]f32
    char* B1 = ws + alloc((size_t)HW * 256 * 2);
    // B2: Y1c; later fbc
    char* B2 = ws + alloc((size_t)HW * 256 * 2);
    float* ccv  = (float*)(ws + alloc((size_t)32 * HW * 4));
    unsigned short* Wt1s = (unsigned short*)(ws + alloc((size_t)9 * 256 * 512 * 2));
    unsigned short* Wt2s = (unsigned short*)(ws + alloc((size_t)9 * 128 * 256 * 2));
    unsigned short* Wt3s = (unsigned short*)(ws + alloc((size_t)9 * 32 * 128 * 2));
    unsigned short* Wt1c = (unsigned short*)(ws + alloc((size_t)9 * 256 * 512 * 2));
    unsigned short* Wt2c = (unsigned short*)(ws + alloc((size_t)9 * 128 * 256 * 2));
    unsigned short* Wt3c = (unsigned short*)(ws + alloc((size_t)9 * 32 * 128 * 2));
    unsigned short* Wc  = (unsigned short*)(ws + alloc((size_t)32 * 512 * 2));
    unsigned char* ccode = (unsigned char*)(ws + alloc(HW));
    unsigned char* scode = (unsigned char*)(ws + alloc(HW));
    signed char* cidx = (signed char*)(ws + alloc(HW));
    signed char* sidx = (signed char*)(ws + alloc(HW));
    signed char* fidx = (signed char*)(ws + alloc(HW));
    int*   cnt    = (int*)(ws + alloc(8 * 4));
    float* cmean5 = (float*)(ws + alloc(5 * CDIM * 4));
    float* smean5 = (float*)(ws + alloc(5 * CDIM * 4));
    float* covraw = (float*)(ws + alloc(8 * 1024 * 4));
    float* sMats  = (float*)(ws + alloc(4 * 1024 * 4));
    float* cMats  = (float*)(ws + alloc(4 * 1024 * 4));
    float* tm5    = (float*)(ws + alloc(5 * 1024 * 4));
    float* B5     = (float*)(ws + alloc(5 * 512 * 4));
    float* zpf    = (float*)(ws + alloc(256));
    (void)ws_size; (void)n_in; (void)out_size;

    unsigned short* Xt  = (unsigned short*)regA;
    unsigned short* Y2s = (unsigned short*)regA;                          // after Xt dead
    unsigned short* Y2c = (unsigned short*)(regA + (size_t)HW * 128 * 2);
    unsigned short* Y1s = (unsigned short*)B1;
    unsigned short* Y1c = (unsigned short*)B2;
    float* fbs = (float*)B1;                                              // after Y1s dead
    float* fbc = (float*)B2;
    const unsigned short* zp = (const unsigned short*)zpf;

    // ---- stage 0 ----
    prep_all_k<<<11905, 256, 0, stream>>>(cnt, covraw, zpf, compress_w, Wc,
                                          snet_w1, Wt1s, snet_w2, Wt2s, snet_w3, Wt3s,
                                          cnet_w1, Wt1c, cnet_w2, Wt2c, cnet_w3, Wt3c);
    pack_masks_k<<<HW / 256, 256, 0, stream>>>(cmasks, smasks, n, ccode, scode, cnt);
    masked_means_k<<<2 * CDIM, 256, 0, stream>>>(cF, sF, ccode, scode, cnt, cmean5, smean5);
    idx_maps_k<<<HW / 256, 256, 0, stream>>>(ccode, scode, cnt, n, cidx, sidx, fidx);

    // ---- conv1 per net (shared Xt buffer) ----
    trans_in_k<<<dim3(HW / 64, 8), 256, 0, stream>>>(sF, smean5, sidx, Xt);
    convmf2_k<512, 256, 128, 128, true><<<1024, 256, 0, stream>>>(
        Xt, Wt1s, snet_b1, Y1s, Xt, Wt1s, snet_b1, Y1s, zp);
    trans_in_k<<<dim3(HW / 64, 8), 256, 0, stream>>>(cF, cmean5, cidx, Xt);
    ccv_gemm_k<<<HW / 256, 256, 0, stream>>>(Xt, Wc, compress_b, ccv);
    convmf2_k<512, 256, 128, 128, true><<<1024, 256, 0, stream>>>(
        Xt, Wt1c, cnet_b1, Y1c, Xt, Wt1c, cnet_b1, Y1c, zp);

    // ---- batched tail: conv2, conv3, cov, fc (both nets per dispatch) ----
    convmf2_k<256, 128, 128, 128, true><<<1024, 256, 0, stream>>>(
        Y1s, Wt2s, snet_b2, Y2s, Y1c, Wt2c, cnet_b2, Y2c, zp);
    convmf_k<128, 32, 32, 256, 32, 64, false><<<512, 256, 0, stream>>>(
        Y2s, Wt3s, snet_b3, fbs, Y2c, Wt3c, cnet_b3, fbc, zp);
    cov_accum_k<<<dim3(HW / 256, n, 2), 256, 0, stream>>>(
        fbs, scode, covraw, fbc, ccode, covraw + 4 * 1024);
    fc_k<<<dim3(256, n, 2), 256, 0, stream>>>(
        snet_fcw, snet_fcb, covraw, cnt + 4, sMats,
        cnet_fcw, cnet_fcb, covraw + 4 * 1024, cnt, cMats);

    // ---- combine ----
    prep_small_k<<<30, 256, 0, stream>>>(sMats, cMats, unzip_b, smean5, n, tm5, B5);
    final_k<<<dim3(HW / 256, 8), 256, 0, stream>>>(ccv, fidx, tm5, B5, unzip_w, out);
}